// Round 4
// baseline (715.488 us; speedup 1.0000x reference)
//
#include <hip/hip_runtime.h>

// MHA forward, MI355X/gfx950 — round 4.
// Changes vs R3 (attention kernel only):
//   1. XCD-aware block swizzle (T1): wgid=(bid&7)*256+bid/8 -> each XCD owns
//      8 (b,h) groups; K/V re-reads become L2 hits (4MB/XCD working set -> 1MB).
//   2. Pass-1 K pipeline 3-deep: Vs+Ps reused as K ring buffers (4x16KB),
//      wait-own-vmcnt THEN barrier THEN issue K(tt+3); counted waits 8/4/0,
//      fully unrolled so immediates are constants. No vmcnt(0) drain per iter.
//   3. Pass 2 identical to R3 (counted vmcnt, stores never drained).

#define DEV __device__ __forceinline__

typedef __attribute__((ext_vector_type(8))) short short8;   // 8 bf16 (MFMA A/B frag)
typedef __attribute__((ext_vector_type(4))) float f32x4;    // MFMA C/D frag

DEV unsigned short f2b(float f) {   // f32 -> bf16 RNE
  union { float f; unsigned u; } v; v.f = f;
  unsigned r = v.u + 0x7fffu + ((v.u >> 16) & 1u);
  return (unsigned short)(r >> 16);
}
DEV unsigned pk2(float lo, float hi) {  // two f32 -> packed bf16x2
  return (unsigned)f2b(lo) | ((unsigned)f2b(hi) << 16);
}
DEV void gl_lds16(const void* g, void* l) {  // async global->LDS, dest = base + lane*16
  __builtin_amdgcn_global_load_lds(
      (const __attribute__((address_space(1))) void*)g,
      (__attribute__((address_space(3))) void*)l, 16, 0, 0);
}
DEV void bar_lgkm() { asm volatile("s_waitcnt lgkmcnt(0)\n\ts_barrier" ::: "memory"); }
DEV void wait_vm0() { asm volatile("s_waitcnt vmcnt(0)" ::: "memory"); }

__global__ void cvt_f32_bf16(const float* __restrict__ src, unsigned short* __restrict__ dst, int n) {
  int i = (blockIdx.x * blockDim.x + threadIdx.x) * 4;
  if (i >= n) return;
  float4 v = *(const float4*)(src + i);
  ushort4 o; o.x = f2b(v.x); o.y = f2b(v.y); o.z = f2b(v.z); o.w = f2b(v.w);
  *(ushort4*)(dst + i) = o;
}

// C = A @ B^T + bias; A[M][K], B[N][K] bf16. 128x128 tile, BK=64, 4 waves (2x2).
// MODE 0: fp32 C (ld=N).  MODE 1: QKV special — n<2048 -> bf16 Cqk (ld 2048,
// q cols scaled 1/8); n>=2048 -> V transposed into Vtg[bh][d][t] (packed 8B).
template<int MODE>
__global__ __launch_bounds__(256, 2) void gemm_bt(
    const unsigned short* __restrict__ A,
    const unsigned short* __restrict__ B,
    const float* __restrict__ bias,
    float* __restrict__ Cf,
    unsigned short* __restrict__ Cqk,
    unsigned short* __restrict__ Vtg,
    int N, int K)
{
  constexpr int BK = 64;
  __shared__ __align__(16) unsigned short As[128*BK];
  __shared__ __align__(16) unsigned short Bs[128*BK];
  const int tid = threadIdx.x, lane = tid & 63, wid = tid >> 6;
  const int lhi = lane >> 4, llo = lane & 15;
  const int m0 = blockIdx.y * 128, n0 = blockIdx.x * 128;
  const int wr = wid >> 1, wc = wid & 1;

  f32x4 acc[4][4] = {};

  const int nsteps = K / BK;
  for (int kt = 0; kt < nsteps; ++kt) {
    __syncthreads();
#pragma unroll
    for (int s = 0; s < 4; ++s) {
      int u = wid*4 + s;
      int a = u*1024 + lane*16;
      int t = a >> 7;
      int cb = (a & 127) ^ ((t & 7) << 4);
      int e = kt*BK + (cb >> 1);
      gl_lds16(A + (size_t)(m0 + t)*K + e, (char*)As + u*1024);
      gl_lds16(B + (size_t)(n0 + t)*K + e, (char*)Bs + u*1024);
    }
    __syncthreads();
#pragma unroll
    for (int kk = 0; kk < 2; ++kk) {
      short8 af[4], bfr[4];
#pragma unroll
      for (int mf = 0; mf < 4; ++mf) {
        int row = wr*64 + mf*16 + llo;
        af[mf] = *(const short8*)((const char*)As + row*128 + ((kk*64 + lhi*16) ^ ((row & 7) << 4)));
      }
#pragma unroll
      for (int nf = 0; nf < 4; ++nf) {
        int row = wc*64 + nf*16 + llo;
        bfr[nf] = *(const short8*)((const char*)Bs + row*128 + ((kk*64 + lhi*16) ^ ((row & 7) << 4)));
      }
#pragma unroll
      for (int mf = 0; mf < 4; ++mf)
#pragma unroll
        for (int nf = 0; nf < 4; ++nf)
          acc[mf][nf] = __builtin_amdgcn_mfma_f32_16x16x32_bf16(af[mf], bfr[nf], acc[mf][nf], 0, 0, 0);
    }
  }
  // epilogue (C/D: row = lhi*4+r, col = llo)
  if (MODE == 0) {
#pragma unroll
    for (int mf = 0; mf < 4; ++mf)
#pragma unroll
      for (int nf = 0; nf < 4; ++nf) {
        int n = n0 + wc*64 + nf*16 + llo;
        float bv = bias[n];
#pragma unroll
        for (int r = 0; r < 4; ++r) {
          int m = m0 + wr*64 + mf*16 + lhi*4 + r;
          Cf[(size_t)m*N + n] = acc[mf][nf][r] + bv;
        }
      }
  } else {
    if (n0 < 2048) {  // Q/K region
#pragma unroll
      for (int mf = 0; mf < 4; ++mf)
#pragma unroll
        for (int nf = 0; nf < 4; ++nf) {
          int n = n0 + wc*64 + nf*16 + llo;
          float bv = bias[n];
          float sc = (n < 1024) ? 0.125f : 1.0f;
#pragma unroll
          for (int r = 0; r < 4; ++r) {
            int m = m0 + wr*64 + mf*16 + lhi*4 + r;
            Cqk[(size_t)m*2048 + n] = f2b((acc[mf][nf][r] + bv) * sc);
          }
        }
    } else {          // V region -> transposed Vtg[bh][d][t]
#pragma unroll
      for (int mf = 0; mf < 4; ++mf)
#pragma unroll
        for (int nf = 0; nf < 4; ++nf) {
          int n = n0 + wc*64 + nf*16 + llo;
          float bv = bias[n];
          int hh = (n - 2048) >> 6, d = (n - 2048) & 63;
          int m = m0 + wr*64 + mf*16 + lhi*4;
          int bb = m >> 11, t = m & 2047;
          ushort4 o;
          o.x = f2b(acc[mf][nf][0] + bv);
          o.y = f2b(acc[mf][nf][1] + bv);
          o.z = f2b(acc[mf][nf][2] + bv);
          o.w = f2b(acc[mf][nf][3] + bv);
          *(ushort4*)(Vtg + ((size_t)((bb << 4) + hh)*64 + d)*2048 + t) = o;
        }
    }
  }
}

// Fused attention. Block = (b,h,qt): 64 q-rows, 4 waves. Wave w owns t-cols
// [w*32,w*32+32) for scores (mfma(K,Q): D[t][q]) and q-rows [w*16,w*16+16)
// for PV (mfma(Vt,P): D[d][q]).
__global__ __launch_bounds__(256, 2) void mha_fused(
    const unsigned short* __restrict__ qk,    // [8192][2048] bf16 (q scaled)
    const unsigned short* __restrict__ vtg,   // [64 bh][64 d][2048 t] bf16
    float* __restrict__ probs,                // [64 bh][2048][2048] f32
    unsigned short* __restrict__ attnb)       // [8192][1024] bf16
{
  constexpr int T = 2048, LD = 2048, QB = 64, TB = 128, NT = T / TB;
  __shared__ __align__(16) unsigned short Qs[QB*64];        //  8 KB
  __shared__ __align__(16) unsigned short Kbuf[2][TB*64];   // 32 KB
  __shared__ __align__(16) unsigned short Vs[64*TB];        // 16 KB
  __shared__ __align__(16) unsigned short Ps[QB*TB];        // 16 KB
  __shared__ float lsum[4][QB];
  __shared__ float linv[QB];

  const int tid = threadIdx.x, lane = tid & 63, wid = tid >> 6;
  const int lhi = lane >> 4, llo = lane & 15;
  // XCD swizzle: consecutive wgid (same bh) land on the same XCD's L2.
  const int wg = ((blockIdx.x & 7) << 8) | (blockIdx.x >> 3);
  const int qt = wg & 31, bh = wg >> 5;
  const int bb = bh >> 4, h = bh & 15;
  const int q0 = qt * QB;
  const size_t tokQ = (size_t)bb*T + q0;

  // Pass-1 K ring: 4 x 16KB (Vs/Ps unused during pass 1)
  unsigned short* kb0 = Kbuf[0];
  unsigned short* kb1 = Kbuf[1];
  unsigned short* kb2 = Vs;
  unsigned short* kb3 = Ps;
  unsigned short* kbuf[4] = {kb0, kb1, kb2, kb3};

  auto stageKb = [&](int tt, unsigned short* base) {
#pragma unroll
    for (int s = 0; s < 4; ++s) {
      int u = wid*4 + s;
      int a = u*1024 + lane*16;
      int tr = a >> 7;
      int cb = (a & 127) ^ ((tr & 7) << 4);
      gl_lds16(qk + ((size_t)bb*T + tt*TB + tr)*LD + 1024 + h*64 + (cb >> 1),
               (char*)base + u*1024);
    }
  };
  auto stageV = [&](int tt) {
#pragma unroll
    for (int s = 0; s < 4; ++s) {
      int u = wid*4 + s;
      int a = u*1024 + lane*16;
      int d = a >> 8;
      int cb = (a & 255) ^ ((d & 7) << 4);
      gl_lds16(vtg + ((size_t)bh*64 + d)*T + tt*TB + (cb >> 1),
               (char*)Vs + u*1024);
    }
  };

  // ---- prologue: Q (8 KB, 2 loads/wave) + K0,K1,K2 ----
#pragma unroll
  for (int s = 0; s < 2; ++s) {
    int u = wid*2 + s;
    int a = u*1024 + lane*16;
    int tr = a >> 7;
    int cb = (a & 127) ^ ((tr & 7) << 4);
    gl_lds16(qk + (tokQ + tr)*LD + h*64 + (cb >> 1), (char*)Qs + u*1024);
  }
  stageKb(0, kb0);
  stageKb(1, kb1);
  stageKb(2, kb2);
  // own Q(2)+K0(4) done (K1,K2 = 8 newer), then all-waves barrier
  asm volatile("s_waitcnt vmcnt(8)\n\ts_barrier" ::: "memory");

  // Q fragments in registers (loop-invariant)
  short8 qfr[4][2];
#pragma unroll
  for (int qf = 0; qf < 4; ++qf)
#pragma unroll
    for (int kk = 0; kk < 2; ++kk) {
      int row = qf*16 + llo;
      qfr[qf][kk] = *(const short8*)((const char*)Qs + row*128 + ((kk*64 + lhi*16) ^ ((row & 7) << 4)));
    }

  // ---------------- pass 1: denominators (3-deep K pipeline) ----------------
  float part[4] = {0.f, 0.f, 0.f, 0.f};
#pragma unroll
  for (int tt = 0; tt < NT; ++tt) {
    // wait own K(tt) (newer tiles allowed in flight), then all-waves barrier
    if (tt + 2 <= NT - 1)      asm volatile("s_waitcnt vmcnt(8) lgkmcnt(0)\n\ts_barrier" ::: "memory");
    else if (tt + 1 <= NT - 1) asm volatile("s_waitcnt vmcnt(4) lgkmcnt(0)\n\ts_barrier" ::: "memory");
    else                       asm volatile("s_waitcnt vmcnt(0) lgkmcnt(0)\n\ts_barrier" ::: "memory");
    // issue K(tt+3) into the buffer freed by iter tt-1
    if (tt + 3 < NT) stageKb(tt + 3, kbuf[(tt + 3) & 3]);
    const unsigned short* kbb = kbuf[tt & 3];
    f32x4 sacc[2][4] = {};
#pragma unroll
    for (int kk = 0; kk < 2; ++kk) {
      short8 kf[2];
#pragma unroll
      for (int tf = 0; tf < 2; ++tf) {
        int row = wid*32 + tf*16 + llo;
        kf[tf] = *(const short8*)((const char*)kbb + row*128 + ((kk*64 + lhi*16) ^ ((row & 7) << 4)));
      }
#pragma unroll
      for (int tf = 0; tf < 2; ++tf)
#pragma unroll
        for (int qf = 0; qf < 4; ++qf)
          sacc[tf][qf] = __builtin_amdgcn_mfma_f32_16x16x32_bf16(kf[tf], qfr[qf][kk], sacc[tf][qf], 0, 0, 0);
    }
#pragma unroll
    for (int tf = 0; tf < 2; ++tf)
#pragma unroll
      for (int qf = 0; qf < 4; ++qf)
#pragma unroll
        for (int r = 0; r < 4; ++r)
          part[qf] += __expf(sacc[tf][qf][r]);
  }

  // wave-local reduce over lhi groups, then cross-wave via LDS
#pragma unroll
  for (int qf = 0; qf < 4; ++qf) {
    float v = part[qf];
    v += __shfl_xor(v, 16);
    v += __shfl_xor(v, 32);
    if (lhi == 0) lsum[wid][qf*16 + llo] = v;
  }
  stageKb(0, kb0);                            // K0 for pass 2
  bar_lgkm();                                 // lsum visible
  if (tid < QB) linv[tid] = 1.0f / (lsum[0][tid] + lsum[1][tid] + lsum[2][tid] + lsum[3][tid]);
  stageV(0);                                  // V0
  stageKb(1, kb1);                            // K1
  asm volatile("s_waitcnt vmcnt(8)" ::: "memory");   // own K0 done (V0+K1 = 8 newer)
  bar_lgkm();                                 // linv visible + all K0 landed
  float lr[4];
#pragma unroll
  for (int qf = 0; qf < 4; ++qf) lr[qf] = linv[qf*16 + llo];

  // ---------------- pass 2: probs + PV (counted vmcnt) ----------------
  f32x4 pv[4] = {};
  for (int tt = 0; tt < NT; ++tt) {
    // A: scores from Kbuf[tt&1]
    f32x4 sacc[2][4] = {};
#pragma unroll
    for (int kk = 0; kk < 2; ++kk) {
      short8 kf[2];
#pragma unroll
      for (int tf = 0; tf < 2; ++tf) {
        int row = wid*32 + tf*16 + llo;
        kf[tf] = *(const short8*)((const char*)Kbuf[tt & 1] + row*128 + ((kk*64 + lhi*16) ^ ((row & 7) << 4)));
      }
#pragma unroll
      for (int tf = 0; tf < 2; ++tf)
#pragma unroll
        for (int qf = 0; qf < 4; ++qf)
          sacc[tf][qf] = __builtin_amdgcn_mfma_f32_16x16x32_bf16(kf[tf], qfr[qf][kk], sacc[tf][qf], 0, 0, 0);
    }
    // B: exp, normalize, pack Ps (b64), stash probs values
    float4 pst[2][4];
#pragma unroll
    for (int tf = 0; tf < 2; ++tf)
#pragma unroll
      for (int qf = 0; qf < 4; ++qf) {
        float p0 = __expf(sacc[tf][qf][0]) * lr[qf];
        float p1 = __expf(sacc[tf][qf][1]) * lr[qf];
        float p2 = __expf(sacc[tf][qf][2]) * lr[qf];
        float p3 = __expf(sacc[tf][qf][3]) * lr[qf];
        int q = qf*16 + llo;
        int t0 = wid*32 + tf*16 + lhi*4;
        uint2 w2; w2.x = pk2(p0, p1); w2.y = pk2(p2, p3);
        *(uint2*)((char*)Ps + q*256 + ((t0*2) ^ ((q & 7) << 4))) = w2;
        pst[tf][qf] = make_float4(8.f*p0, 8.f*p1, 8.f*p2, 8.f*p3);
      }
    // B1: own V(tt) landed (stores/K may fly), then barrier
    if (tt == 0) asm volatile("s_waitcnt vmcnt(4) lgkmcnt(0)\n\ts_barrier" ::: "memory");
    else         asm volatile("s_waitcnt vmcnt(12) lgkmcnt(0)\n\ts_barrier" ::: "memory");
    // D: PV (reads Ps + Vs)
#pragma unroll
    for (int kk2 = 0; kk2 < 4; ++kk2) {
      int rq = wid*16 + llo;
      short8 pb = *(const short8*)((const char*)Ps + rq*256 + ((kk2*64 + lhi*16) ^ ((rq & 7) << 4)));
#pragma unroll
      for (int mf = 0; mf < 4; ++mf) {
        int rd = mf*16 + llo;
        short8 va = *(const short8*)((const char*)Vs + rd*256 + ((kk2*64 + lhi*16) ^ ((rd & 7) << 4)));
        pv[mf] = __builtin_amdgcn_mfma_f32_16x16x32_bf16(va, pb, pv[mf], 0, 0, 0);
      }
    }
    // B2: own K(tt+1) landed (stores may fly), then barrier
    if (tt == 0) asm volatile("s_waitcnt vmcnt(0)\n\ts_barrier" ::: "memory");
    else         asm volatile("s_waitcnt vmcnt(8)\n\ts_barrier" ::: "memory");
    // F: issue next-tile loads FIRST, then stores (order pinned by fences)
    stageV((tt + 1) & 15);                        // dummy wrap at tt=15 (never read)
    asm volatile("" ::: "memory");
    stageKb((tt + 2) & 15, Kbuf[tt & 1]);         // dummy wrap at tt>=14 (never read)
    asm volatile("" ::: "memory");
#pragma unroll
    for (int tf = 0; tf < 2; ++tf)
#pragma unroll
      for (int qf = 0; qf < 4; ++qf) {
        int q = qf*16 + llo;
        int t0 = wid*32 + tf*16 + lhi*4;
        *(float4*)&probs[((size_t)bh*T + q0 + q)*T + tt*TB + t0] = pst[tf][qf];
      }
  }

  // attn out: D[d][q], lane has 4 consecutive d at q = wid*16+llo
#pragma unroll
  for (int mf = 0; mf < 4; ++mf) {
    int q = wid*16 + llo;
    int d0 = mf*16 + lhi*4;
    ushort4 o;
    o.x = f2b(pv[mf][0]); o.y = f2b(pv[mf][1]);
    o.z = f2b(pv[mf][2]); o.w = f2b(pv[mf][3]);
    *(ushort4*)(attnb + (tokQ + q)*1024 + h*64 + d0) = o;
  }
}

extern "C" void kernel_launch(void* const* d_in, const int* in_sizes, int n_in,
                              void* d_out, int out_size, void* d_ws, size_t ws_size,
                              hipStream_t stream) {
  (void)in_sizes; (void)n_in; (void)out_size; (void)ws_size;
  const float* x    = (const float*)d_in[0];
  const float* wqkv = (const float*)d_in[1];
  const float* bqkv = (const float*)d_in[2];
  const float* wout = (const float*)d_in[3];
  const float* bout = (const float*)d_in[4];

  constexpr int T = 2048, E = 1024;
  constexpr int M = 4 * T;
  constexpr size_t NX   = (size_t)M * E;
  constexpr size_t NW1  = (size_t)3 * E * E;
  constexpr size_t NW2  = (size_t)E * E;
  constexpr size_t NQK  = (size_t)M * 2048;
  constexpr size_t NVT  = (size_t)64 * 64 * T;

  char* ws = (char*)d_ws;
  unsigned short* xb    = (unsigned short*)ws;  ws += NX  * 2;
  unsigned short* wqkvb = (unsigned short*)ws;  ws += NW1 * 2;
  unsigned short* woutb = (unsigned short*)ws;  ws += NW2 * 2;
  unsigned short* qkb   = (unsigned short*)ws;  ws += NQK * 2;
  unsigned short* vtg   = (unsigned short*)ws;  ws += NVT * 2;
  unsigned short* attnb = (unsigned short*)ws;  ws += NX  * 2;

  cvt_f32_bf16<<<(int)(NX  / 1024), 256, 0, stream>>>(x,    xb,    (int)NX);
  cvt_f32_bf16<<<(int)(NW1 / 1024), 256, 0, stream>>>(wqkv, wqkvb, (int)NW1);
  cvt_f32_bf16<<<(int)(NW2 / 1024), 256, 0, stream>>>(wout, woutb, (int)NW2);

  gemm_bt<1><<<dim3(3*E/128, M/128), 256, 0, stream>>>(
      xb, wqkvb, bqkv, nullptr, qkb, vtg, 3*E, E);

  float* probsOut = (float*)d_out + NX;
  mha_fused<<<4*16*(T/64), 256, 0, stream>>>(qkb, vtg, probsOut, attnb);

  gemm_bt<0><<<dim3(E/128, M/128), 256, 0, stream>>>(
      attnb, woutb, bout, (float*)d_out, nullptr, nullptr, E, E);
}

// Round 5
// 524.767 us; speedup vs baseline: 1.3634x; 1.3634x over previous
//
#include <hip/hip_runtime.h>

// MHA forward, MI355X/gfx950 — round 5.
// R4 post-mortem: bundled {XCD swizzle, pass-1 3-deep unrolled pipeline} lost
// 172us. Leading suspect: the unrolled pass-1 pipeline (code bloat / VGPR
// pressure at the launch_bounds cap -> spills). This round: EXACT R3 kernel
// + ONLY the XCD-aware block swizzle (T1). Single-change attribution.

#define DEV __device__ __forceinline__

typedef __attribute__((ext_vector_type(8))) short short8;   // 8 bf16 (MFMA A/B frag)
typedef __attribute__((ext_vector_type(4))) float f32x4;    // MFMA C/D frag

DEV unsigned short f2b(float f) {   // f32 -> bf16 RNE
  union { float f; unsigned u; } v; v.f = f;
  unsigned r = v.u + 0x7fffu + ((v.u >> 16) & 1u);
  return (unsigned short)(r >> 16);
}
DEV unsigned pk2(float lo, float hi) {  // two f32 -> packed bf16x2
  return (unsigned)f2b(lo) | ((unsigned)f2b(hi) << 16);
}
DEV void gl_lds16(const void* g, void* l) {  // async global->LDS, dest = base + lane*16
  __builtin_amdgcn_global_load_lds(
      (const __attribute__((address_space(1))) void*)g,
      (__attribute__((address_space(3))) void*)l, 16, 0, 0);
}
DEV void bar_lgkm() { asm volatile("s_waitcnt lgkmcnt(0)\n\ts_barrier" ::: "memory"); }
DEV void wait_vm0() { asm volatile("s_waitcnt vmcnt(0)" ::: "memory"); }

__global__ void cvt_f32_bf16(const float* __restrict__ src, unsigned short* __restrict__ dst, int n) {
  int i = (blockIdx.x * blockDim.x + threadIdx.x) * 4;
  if (i >= n) return;
  float4 v = *(const float4*)(src + i);
  ushort4 o; o.x = f2b(v.x); o.y = f2b(v.y); o.z = f2b(v.z); o.w = f2b(v.w);
  *(ushort4*)(dst + i) = o;
}

// C = A @ B^T + bias; A[M][K], B[N][K] bf16. 128x128 tile, BK=64, 4 waves (2x2).
// MODE 0: fp32 C (ld=N).  MODE 1: QKV special — n<2048 -> bf16 Cqk (ld 2048,
// q cols scaled 1/8); n>=2048 -> V transposed into Vtg[bh][d][t] (packed 8B).
template<int MODE>
__global__ __launch_bounds__(256, 2) void gemm_bt(
    const unsigned short* __restrict__ A,
    const unsigned short* __restrict__ B,
    const float* __restrict__ bias,
    float* __restrict__ Cf,
    unsigned short* __restrict__ Cqk,
    unsigned short* __restrict__ Vtg,
    int N, int K)
{
  constexpr int BK = 64;
  __shared__ __align__(16) unsigned short As[128*BK];
  __shared__ __align__(16) unsigned short Bs[128*BK];
  const int tid = threadIdx.x, lane = tid & 63, wid = tid >> 6;
  const int lhi = lane >> 4, llo = lane & 15;
  const int m0 = blockIdx.y * 128, n0 = blockIdx.x * 128;
  const int wr = wid >> 1, wc = wid & 1;

  f32x4 acc[4][4] = {};

  const int nsteps = K / BK;
  for (int kt = 0; kt < nsteps; ++kt) {
    __syncthreads();
#pragma unroll
    for (int s = 0; s < 4; ++s) {
      int u = wid*4 + s;
      int a = u*1024 + lane*16;
      int t = a >> 7;
      int cb = (a & 127) ^ ((t & 7) << 4);
      int e = kt*BK + (cb >> 1);
      gl_lds16(A + (size_t)(m0 + t)*K + e, (char*)As + u*1024);
      gl_lds16(B + (size_t)(n0 + t)*K + e, (char*)Bs + u*1024);
    }
    __syncthreads();
#pragma unroll
    for (int kk = 0; kk < 2; ++kk) {
      short8 af[4], bfr[4];
#pragma unroll
      for (int mf = 0; mf < 4; ++mf) {
        int row = wr*64 + mf*16 + llo;
        af[mf] = *(const short8*)((const char*)As + row*128 + ((kk*64 + lhi*16) ^ ((row & 7) << 4)));
      }
#pragma unroll
      for (int nf = 0; nf < 4; ++nf) {
        int row = wc*64 + nf*16 + llo;
        bfr[nf] = *(const short8*)((const char*)Bs + row*128 + ((kk*64 + lhi*16) ^ ((row & 7) << 4)));
      }
#pragma unroll
      for (int mf = 0; mf < 4; ++mf)
#pragma unroll
        for (int nf = 0; nf < 4; ++nf)
          acc[mf][nf] = __builtin_amdgcn_mfma_f32_16x16x32_bf16(af[mf], bfr[nf], acc[mf][nf], 0, 0, 0);
    }
  }
  // epilogue (C/D: row = lhi*4+r, col = llo)
  if (MODE == 0) {
#pragma unroll
    for (int mf = 0; mf < 4; ++mf)
#pragma unroll
      for (int nf = 0; nf < 4; ++nf) {
        int n = n0 + wc*64 + nf*16 + llo;
        float bv = bias[n];
#pragma unroll
        for (int r = 0; r < 4; ++r) {
          int m = m0 + wr*64 + mf*16 + lhi*4 + r;
          Cf[(size_t)m*N + n] = acc[mf][nf][r] + bv;
        }
      }
  } else {
    if (n0 < 2048) {  // Q/K region
#pragma unroll
      for (int mf = 0; mf < 4; ++mf)
#pragma unroll
        for (int nf = 0; nf < 4; ++nf) {
          int n = n0 + wc*64 + nf*16 + llo;
          float bv = bias[n];
          float sc = (n < 1024) ? 0.125f : 1.0f;
#pragma unroll
          for (int r = 0; r < 4; ++r) {
            int m = m0 + wr*64 + mf*16 + lhi*4 + r;
            Cqk[(size_t)m*2048 + n] = f2b((acc[mf][nf][r] + bv) * sc);
          }
        }
    } else {          // V region -> transposed Vtg[bh][d][t]
#pragma unroll
      for (int mf = 0; mf < 4; ++mf)
#pragma unroll
        for (int nf = 0; nf < 4; ++nf) {
          int n = n0 + wc*64 + nf*16 + llo;
          float bv = bias[n];
          int hh = (n - 2048) >> 6, d = (n - 2048) & 63;
          int m = m0 + wr*64 + mf*16 + lhi*4;
          int bb = m >> 11, t = m & 2047;
          ushort4 o;
          o.x = f2b(acc[mf][nf][0] + bv);
          o.y = f2b(acc[mf][nf][1] + bv);
          o.z = f2b(acc[mf][nf][2] + bv);
          o.w = f2b(acc[mf][nf][3] + bv);
          *(ushort4*)(Vtg + ((size_t)((bb << 4) + hh)*64 + d)*2048 + t) = o;
        }
    }
  }
}

// Fused attention. Block = (b,h,qt): 64 q-rows, 4 waves. Wave w owns t-cols
// [w*32,w*32+32) for scores (mfma(K,Q): D[t][q]) and q-rows [w*16,w*16+16)
// for PV (mfma(Vt,P): D[d][q]).
__global__ __launch_bounds__(256, 2) void mha_fused(
    const unsigned short* __restrict__ qk,    // [8192][2048] bf16 (q scaled)
    const unsigned short* __restrict__ vtg,   // [64 bh][64 d][2048 t] bf16
    float* __restrict__ probs,                // [64 bh][2048][2048] f32
    unsigned short* __restrict__ attnb)       // [8192][1024] bf16
{
  constexpr int T = 2048, LD = 2048, QB = 64, TB = 128, NT = T / TB;
  __shared__ __align__(16) unsigned short Qs[QB*64];        //  8 KB
  __shared__ __align__(16) unsigned short Kbuf[2][TB*64];   // 32 KB
  __shared__ __align__(16) unsigned short Vs[64*TB];        // 16 KB
  __shared__ __align__(16) unsigned short Ps[QB*TB];        // 16 KB
  __shared__ float lsum[4][QB];
  __shared__ float linv[QB];

  const int tid = threadIdx.x, lane = tid & 63, wid = tid >> 6;
  const int lhi = lane >> 4, llo = lane & 15;
  // XCD swizzle (T1): wgid = (bid%8)*256 + bid/8 (bijective, 2048%8==0).
  // Consecutive wgid (same bh) land on the same XCD's L2.
  const int wg = ((blockIdx.x & 7) << 8) | (blockIdx.x >> 3);
  const int qt = wg & 31, bh = wg >> 5;
  const int bb = bh >> 4, h = bh & 15;
  const int q0 = qt * QB;
  const size_t tokQ = (size_t)bb*T + q0;

  auto stageK = [&](int tt, unsigned short* buf) {
#pragma unroll
    for (int s = 0; s < 4; ++s) {
      int u = wid*4 + s;
      int a = u*1024 + lane*16;
      int tr = a >> 7;
      int cb = (a & 127) ^ ((tr & 7) << 4);
      gl_lds16(qk + ((size_t)bb*T + tt*TB + tr)*LD + 1024 + h*64 + (cb >> 1),
               (char*)buf + u*1024);
    }
  };
  auto stageV = [&](int tt) {
#pragma unroll
    for (int s = 0; s < 4; ++s) {
      int u = wid*4 + s;
      int a = u*1024 + lane*16;
      int d = a >> 8;
      int cb = (a & 255) ^ ((d & 7) << 4);
      gl_lds16(vtg + ((size_t)bh*64 + d)*T + tt*TB + (cb >> 1),
               (char*)Vs + u*1024);
    }
  };

  // ---- prologue: Q (8 KB) + K0 ----
#pragma unroll
  for (int s = 0; s < 2; ++s) {
    int u = wid*2 + s;
    int a = u*1024 + lane*16;
    int tr = a >> 7;
    int cb = (a & 127) ^ ((tr & 7) << 4);
    gl_lds16(qk + (tokQ + tr)*LD + h*64 + (cb >> 1), (char*)Qs + u*1024);
  }
  stageK(0, Kbuf[0]);
  wait_vm0(); bar_lgkm();

  // Q fragments in registers (loop-invariant)
  short8 qfr[4][2];
#pragma unroll
  for (int qf = 0; qf < 4; ++qf)
#pragma unroll
    for (int kk = 0; kk < 2; ++kk) {
      int row = qf*16 + llo;
      qfr[qf][kk] = *(const short8*)((const char*)Qs + row*128 + ((kk*64 + lhi*16) ^ ((row & 7) << 4)));
    }

  // ---------------- pass 1: denominators ----------------
  float part[4] = {0.f, 0.f, 0.f, 0.f};
  for (int tt = 0; tt < NT; ++tt) {
    if (tt + 1 < NT) stageK(tt + 1, Kbuf[(tt + 1) & 1]);
    f32x4 sacc[2][4] = {};
#pragma unroll
    for (int kk = 0; kk < 2; ++kk) {
      short8 kf[2];
#pragma unroll
      for (int tf = 0; tf < 2; ++tf) {
        int row = wid*32 + tf*16 + llo;
        kf[tf] = *(const short8*)((const char*)Kbuf[tt & 1] + row*128 + ((kk*64 + lhi*16) ^ ((row & 7) << 4)));
      }
#pragma unroll
      for (int tf = 0; tf < 2; ++tf)
#pragma unroll
        for (int qf = 0; qf < 4; ++qf)
          sacc[tf][qf] = __builtin_amdgcn_mfma_f32_16x16x32_bf16(kf[tf], qfr[qf][kk], sacc[tf][qf], 0, 0, 0);
    }
#pragma unroll
    for (int tf = 0; tf < 2; ++tf)
#pragma unroll
      for (int qf = 0; qf < 4; ++qf)
#pragma unroll
        for (int r = 0; r < 4; ++r)
          part[qf] += __expf(sacc[tf][qf][r]);
    wait_vm0(); bar_lgkm();
  }

  // wave-local reduce over lhi groups, then cross-wave via LDS
#pragma unroll
  for (int qf = 0; qf < 4; ++qf) {
    float v = part[qf];
    v += __shfl_xor(v, 16);
    v += __shfl_xor(v, 32);
    if (lhi == 0) lsum[wid][qf*16 + llo] = v;
  }
  stageK(0, Kbuf[0]);                         // K0 for pass 2
  bar_lgkm();                                 // lsum visible
  if (tid < QB) linv[tid] = 1.0f / (lsum[0][tid] + lsum[1][tid] + lsum[2][tid] + lsum[3][tid]);
  stageV(0);                                  // V0
  stageK(1, Kbuf[1]);                         // K1
  asm volatile("s_waitcnt vmcnt(8)" ::: "memory");   // own K0 done (V0+K1 = 8 newer)
  bar_lgkm();                                 // linv visible
  float lr[4];
#pragma unroll
  for (int qf = 0; qf < 4; ++qf) lr[qf] = linv[qf*16 + llo];

  // ---------------- pass 2: probs + PV (counted vmcnt) ----------------
  f32x4 pv[4] = {};
  for (int tt = 0; tt < NT; ++tt) {
    // A: scores from Kbuf[tt&1]
    f32x4 sacc[2][4] = {};
#pragma unroll
    for (int kk = 0; kk < 2; ++kk) {
      short8 kf[2];
#pragma unroll
      for (int tf = 0; tf < 2; ++tf) {
        int row = wid*32 + tf*16 + llo;
        kf[tf] = *(const short8*)((const char*)Kbuf[tt & 1] + row*128 + ((kk*64 + lhi*16) ^ ((row & 7) << 4)));
      }
#pragma unroll
      for (int tf = 0; tf < 2; ++tf)
#pragma unroll
        for (int qf = 0; qf < 4; ++qf)
          sacc[tf][qf] = __builtin_amdgcn_mfma_f32_16x16x32_bf16(kf[tf], qfr[qf][kk], sacc[tf][qf], 0, 0, 0);
    }
    // B: exp, normalize, pack Ps (b64), stash probs values
    float4 pst[2][4];
#pragma unroll
    for (int tf = 0; tf < 2; ++tf)
#pragma unroll
      for (int qf = 0; qf < 4; ++qf) {
        float p0 = __expf(sacc[tf][qf][0]) * lr[qf];
        float p1 = __expf(sacc[tf][qf][1]) * lr[qf];
        float p2 = __expf(sacc[tf][qf][2]) * lr[qf];
        float p3 = __expf(sacc[tf][qf][3]) * lr[qf];
        int q = qf*16 + llo;
        int t0 = wid*32 + tf*16 + lhi*4;
        uint2 w2; w2.x = pk2(p0, p1); w2.y = pk2(p2, p3);
        *(uint2*)((char*)Ps + q*256 + ((t0*2) ^ ((q & 7) << 4))) = w2;
        pst[tf][qf] = make_float4(8.f*p0, 8.f*p1, 8.f*p2, 8.f*p3);
      }
    // B1: own V(tt) landed (stores/K may fly), then barrier
    if (tt == 0) asm volatile("s_waitcnt vmcnt(4) lgkmcnt(0)\n\ts_barrier" ::: "memory");
    else         asm volatile("s_waitcnt vmcnt(12) lgkmcnt(0)\n\ts_barrier" ::: "memory");
    // D: PV (reads Ps + Vs)
#pragma unroll
    for (int kk2 = 0; kk2 < 4; ++kk2) {
      int rq = wid*16 + llo;
      short8 pb = *(const short8*)((const char*)Ps + rq*256 + ((kk2*64 + lhi*16) ^ ((rq & 7) << 4)));
#pragma unroll
      for (int mf = 0; mf < 4; ++mf) {
        int rd = mf*16 + llo;
        short8 va = *(const short8*)((const char*)Vs + rd*256 + ((kk2*64 + lhi*16) ^ ((rd & 7) << 4)));
        pv[mf] = __builtin_amdgcn_mfma_f32_16x16x32_bf16(va, pb, pv[mf], 0, 0, 0);
      }
    }
    // B2: own K(tt+1) landed (stores may fly), then barrier
    if (tt == 0) asm volatile("s_waitcnt vmcnt(0)\n\ts_barrier" ::: "memory");
    else         asm volatile("s_waitcnt vmcnt(8)\n\ts_barrier" ::: "memory");
    // F: issue next-tile loads FIRST, then stores (order pinned by fences)
    stageV((tt + 1) & 15);                        // dummy wrap at tt=15 (never read)
    asm volatile("" ::: "memory");
    stageK((tt + 2) & 15, Kbuf[tt & 1]);          // dummy wrap at tt>=14 (never read)
    asm volatile("" ::: "memory");
#pragma unroll
    for (int tf = 0; tf < 2; ++tf)
#pragma unroll
      for (int qf = 0; qf < 4; ++qf) {
        int q = qf*16 + llo;
        int t0 = wid*32 + tf*16 + lhi*4;
        *(float4*)&probs[((size_t)bh*T + q0 + q)*T + tt*TB + t0] = pst[tf][qf];
      }
  }

  // attn out: D[d][q], lane has 4 consecutive d at q = wid*16+llo
#pragma unroll
  for (int mf = 0; mf < 4; ++mf) {
    int q = wid*16 + llo;
    int d0 = mf*16 + lhi*4;
    ushort4 o;
    o.x = f2b(pv[mf][0]); o.y = f2b(pv[mf][1]);
    o.z = f2b(pv[mf][2]); o.w = f2b(pv[mf][3]);
    *(ushort4*)(attnb + (tokQ + q)*1024 + h*64 + d0) = o;
  }
}

extern "C" void kernel_launch(void* const* d_in, const int* in_sizes, int n_in,
                              void* d_out, int out_size, void* d_ws, size_t ws_size,
                              hipStream_t stream) {
  (void)in_sizes; (void)n_in; (void)out_size; (void)ws_size;
  const float* x    = (const float*)d_in[0];
  const float* wqkv = (const float*)d_in[1];
  const float* bqkv = (const float*)d_in[2];
  const float* wout = (const float*)d_in[3];
  const float* bout = (const float*)d_in[4];

  constexpr int T = 2048, E = 1024;
  constexpr int M = 4 * T;
  constexpr size_t NX   = (size_t)M * E;
  constexpr size_t NW1  = (size_t)3 * E * E;
  constexpr size_t NW2  = (size_t)E * E;
  constexpr size_t NQK  = (size_t)M * 2048;
  constexpr size_t NVT  = (size_t)64 * 64 * T;

  char* ws = (char*)d_ws;
  unsigned short* xb    = (unsigned short*)ws;  ws += NX  * 2;
  unsigned short* wqkvb = (unsigned short*)ws;  ws += NW1 * 2;
  unsigned short* woutb = (unsigned short*)ws;  ws += NW2 * 2;
  unsigned short* qkb   = (unsigned short*)ws;  ws += NQK * 2;
  unsigned short* vtg   = (unsigned short*)ws;  ws += NVT * 2;
  unsigned short* attnb = (unsigned short*)ws;  ws += NX  * 2;

  cvt_f32_bf16<<<(int)(NX  / 1024), 256, 0, stream>>>(x,    xb,    (int)NX);
  cvt_f32_bf16<<<(int)(NW1 / 1024), 256, 0, stream>>>(wqkv, wqkvb, (int)NW1);
  cvt_f32_bf16<<<(int)(NW2 / 1024), 256, 0, stream>>>(wqkv == wout ? wout : wout, woutb, (int)NW2);

  gemm_bt<1><<<dim3(3*E/128, M/128), 256, 0, stream>>>(
      xb, wqkvb, bqkv, nullptr, qkb, vtg, 3*E, E);

  float* probsOut = (float*)d_out + NX;
  mha_fused<<<4*16*(T/64), 256, 0, stream>>>(qkb, vtg, probsOut, attnb);

  gemm_bt<0><<<dim3(E/128, M/128), 256, 0, stream>>>(
      attnb, woutb, bout, (float*)d_out, nullptr, nullptr, E, E);
}

// Round 7
// 425.985 us; speedup vs baseline: 1.6796x; 1.2319x over previous
//
#include <hip/hip_runtime.h>

// MHA forward, MI355X/gfx950 — round 7 (= R6 retry, compile fix).
// Change vs R5 (single bucket): NONTEMPORAL stores for the two write-only
// streams — probs (1.07 GB) and final out (33 MB). Mechanism: probs stream
// write-allocates through L2 (thrashing K/V residency per XCD) and its slow
// store-retirement is drained at every B1 barrier (vmcnt FIFO: stores older
// than the V loads we wait on). nt = stream past L2, faster retire.
// Fix vs R6: __builtin_nontemporal_store needs clang ext-vector types, not
// HIP_vector_type float4 -> use f32x4 for the probs stash + store.

#define DEV __device__ __forceinline__

typedef __attribute__((ext_vector_type(8))) short short8;   // 8 bf16 (MFMA A/B frag)
typedef __attribute__((ext_vector_type(4))) float f32x4;    // MFMA C/D frag

DEV unsigned short f2b(float f) {   // f32 -> bf16 RNE
  union { float f; unsigned u; } v; v.f = f;
  unsigned r = v.u + 0x7fffu + ((v.u >> 16) & 1u);
  return (unsigned short)(r >> 16);
}
DEV unsigned pk2(float lo, float hi) {  // two f32 -> packed bf16x2
  return (unsigned)f2b(lo) | ((unsigned)f2b(hi) << 16);
}
DEV void gl_lds16(const void* g, void* l) {  // async global->LDS, dest = base + lane*16
  __builtin_amdgcn_global_load_lds(
      (const __attribute__((address_space(1))) void*)g,
      (__attribute__((address_space(3))) void*)l, 16, 0, 0);
}
DEV void bar_lgkm() { asm volatile("s_waitcnt lgkmcnt(0)\n\ts_barrier" ::: "memory"); }
DEV void wait_vm0() { asm volatile("s_waitcnt vmcnt(0)" ::: "memory"); }

__global__ void cvt_f32_bf16(const float* __restrict__ src, unsigned short* __restrict__ dst, int n) {
  int i = (blockIdx.x * blockDim.x + threadIdx.x) * 4;
  if (i >= n) return;
  float4 v = *(const float4*)(src + i);
  ushort4 o; o.x = f2b(v.x); o.y = f2b(v.y); o.z = f2b(v.z); o.w = f2b(v.w);
  *(ushort4*)(dst + i) = o;
}

// C = A @ B^T + bias; A[M][K], B[N][K] bf16. 128x128 tile, BK=64, 4 waves (2x2).
// MODE 0: fp32 C (ld=N, nontemporal).  MODE 1: QKV special — n<2048 -> bf16 Cqk
// (ld 2048, q cols scaled 1/8); n>=2048 -> V transposed into Vtg[bh][d][t].
template<int MODE>
__global__ __launch_bounds__(256, 2) void gemm_bt(
    const unsigned short* __restrict__ A,
    const unsigned short* __restrict__ B,
    const float* __restrict__ bias,
    float* __restrict__ Cf,
    unsigned short* __restrict__ Cqk,
    unsigned short* __restrict__ Vtg,
    int N, int K)
{
  constexpr int BK = 64;
  __shared__ __align__(16) unsigned short As[128*BK];
  __shared__ __align__(16) unsigned short Bs[128*BK];
  const int tid = threadIdx.x, lane = tid & 63, wid = tid >> 6;
  const int lhi = lane >> 4, llo = lane & 15;
  const int m0 = blockIdx.y * 128, n0 = blockIdx.x * 128;
  const int wr = wid >> 1, wc = wid & 1;

  f32x4 acc[4][4] = {};

  const int nsteps = K / BK;
  for (int kt = 0; kt < nsteps; ++kt) {
    __syncthreads();
#pragma unroll
    for (int s = 0; s < 4; ++s) {
      int u = wid*4 + s;
      int a = u*1024 + lane*16;
      int t = a >> 7;
      int cb = (a & 127) ^ ((t & 7) << 4);
      int e = kt*BK + (cb >> 1);
      gl_lds16(A + (size_t)(m0 + t)*K + e, (char*)As + u*1024);
      gl_lds16(B + (size_t)(n0 + t)*K + e, (char*)Bs + u*1024);
    }
    __syncthreads();
#pragma unroll
    for (int kk = 0; kk < 2; ++kk) {
      short8 af[4], bfr[4];
#pragma unroll
      for (int mf = 0; mf < 4; ++mf) {
        int row = wr*64 + mf*16 + llo;
        af[mf] = *(const short8*)((const char*)As + row*128 + ((kk*64 + lhi*16) ^ ((row & 7) << 4)));
      }
#pragma unroll
      for (int nf = 0; nf < 4; ++nf) {
        int row = wc*64 + nf*16 + llo;
        bfr[nf] = *(const short8*)((const char*)Bs + row*128 + ((kk*64 + lhi*16) ^ ((row & 7) << 4)));
      }
#pragma unroll
      for (int mf = 0; mf < 4; ++mf)
#pragma unroll
        for (int nf = 0; nf < 4; ++nf)
          acc[mf][nf] = __builtin_amdgcn_mfma_f32_16x16x32_bf16(af[mf], bfr[nf], acc[mf][nf], 0, 0, 0);
    }
  }
  // epilogue (C/D: row = lhi*4+r, col = llo)
  if (MODE == 0) {
#pragma unroll
    for (int mf = 0; mf < 4; ++mf)
#pragma unroll
      for (int nf = 0; nf < 4; ++nf) {
        int n = n0 + wc*64 + nf*16 + llo;
        float bv = bias[n];
#pragma unroll
        for (int r = 0; r < 4; ++r) {
          int m = m0 + wr*64 + mf*16 + lhi*4 + r;
          __builtin_nontemporal_store(acc[mf][nf][r] + bv, &Cf[(size_t)m*N + n]);
        }
      }
  } else {
    if (n0 < 2048) {  // Q/K region
#pragma unroll
      for (int mf = 0; mf < 4; ++mf)
#pragma unroll
        for (int nf = 0; nf < 4; ++nf) {
          int n = n0 + wc*64 + nf*16 + llo;
          float bv = bias[n];
          float sc = (n < 1024) ? 0.125f : 1.0f;
#pragma unroll
          for (int r = 0; r < 4; ++r) {
            int m = m0 + wr*64 + mf*16 + lhi*4 + r;
            Cqk[(size_t)m*2048 + n] = f2b((acc[mf][nf][r] + bv) * sc);
          }
        }
    } else {          // V region -> transposed Vtg[bh][d][t]
#pragma unroll
      for (int mf = 0; mf < 4; ++mf)
#pragma unroll
        for (int nf = 0; nf < 4; ++nf) {
          int n = n0 + wc*64 + nf*16 + llo;
          float bv = bias[n];
          int hh = (n - 2048) >> 6, d = (n - 2048) & 63;
          int m = m0 + wr*64 + mf*16 + lhi*4;
          int bb = m >> 11, t = m & 2047;
          ushort4 o;
          o.x = f2b(acc[mf][nf][0] + bv);
          o.y = f2b(acc[mf][nf][1] + bv);
          o.z = f2b(acc[mf][nf][2] + bv);
          o.w = f2b(acc[mf][nf][3] + bv);
          *(ushort4*)(Vtg + ((size_t)((bb << 4) + hh)*64 + d)*2048 + t) = o;
        }
    }
  }
}

// Fused attention. Block = (b,h,qt): 64 q-rows, 4 waves. Wave w owns t-cols
// [w*32,w*32+32) for scores (mfma(K,Q): D[t][q]) and q-rows [w*16,w*16+16)
// for PV (mfma(Vt,P): D[d][q]).
__global__ __launch_bounds__(256, 2) void mha_fused(
    const unsigned short* __restrict__ qk,    // [8192][2048] bf16 (q scaled)
    const unsigned short* __restrict__ vtg,   // [64 bh][64 d][2048 t] bf16
    float* __restrict__ probs,                // [64 bh][2048][2048] f32
    unsigned short* __restrict__ attnb)       // [8192][1024] bf16
{
  constexpr int T = 2048, LD = 2048, QB = 64, TB = 128, NT = T / TB;
  __shared__ __align__(16) unsigned short Qs[QB*64];        //  8 KB
  __shared__ __align__(16) unsigned short Kbuf[2][TB*64];   // 32 KB
  __shared__ __align__(16) unsigned short Vs[64*TB];        // 16 KB
  __shared__ __align__(16) unsigned short Ps[QB*TB];        // 16 KB
  __shared__ float lsum[4][QB];
  __shared__ float linv[QB];

  const int tid = threadIdx.x, lane = tid & 63, wid = tid >> 6;
  const int lhi = lane >> 4, llo = lane & 15;
  // XCD swizzle (T1): wgid = (bid%8)*256 + bid/8 (bijective, 2048%8==0).
  const int wg = ((blockIdx.x & 7) << 8) | (blockIdx.x >> 3);
  const int qt = wg & 31, bh = wg >> 5;
  const int bb = bh >> 4, h = bh & 15;
  const int q0 = qt * QB;
  const size_t tokQ = (size_t)bb*T + q0;

  auto stageK = [&](int tt, unsigned short* buf) {
#pragma unroll
    for (int s = 0; s < 4; ++s) {
      int u = wid*4 + s;
      int a = u*1024 + lane*16;
      int tr = a >> 7;
      int cb = (a & 127) ^ ((tr & 7) << 4);
      gl_lds16(qk + ((size_t)bb*T + tt*TB + tr)*LD + 1024 + h*64 + (cb >> 1),
               (char*)buf + u*1024);
    }
  };
  auto stageV = [&](int tt) {
#pragma unroll
    for (int s = 0; s < 4; ++s) {
      int u = wid*4 + s;
      int a = u*1024 + lane*16;
      int d = a >> 8;
      int cb = (a & 255) ^ ((d & 7) << 4);
      gl_lds16(vtg + ((size_t)bh*64 + d)*T + tt*TB + (cb >> 1),
               (char*)Vs + u*1024);
    }
  };

  // ---- prologue: Q (8 KB) + K0 ----
#pragma unroll
  for (int s = 0; s < 2; ++s) {
    int u = wid*2 + s;
    int a = u*1024 + lane*16;
    int tr = a >> 7;
    int cb = (a & 127) ^ ((tr & 7) << 4);
    gl_lds16(qk + (tokQ + tr)*LD + h*64 + (cb >> 1), (char*)Qs + u*1024);
  }
  stageK(0, Kbuf[0]);
  wait_vm0(); bar_lgkm();

  // Q fragments in registers (loop-invariant)
  short8 qfr[4][2];
#pragma unroll
  for (int qf = 0; qf < 4; ++qf)
#pragma unroll
    for (int kk = 0; kk < 2; ++kk) {
      int row = qf*16 + llo;
      qfr[qf][kk] = *(const short8*)((const char*)Qs + row*128 + ((kk*64 + lhi*16) ^ ((row & 7) << 4)));
    }

  // ---------------- pass 1: denominators ----------------
  float part[4] = {0.f, 0.f, 0.f, 0.f};
  for (int tt = 0; tt < NT; ++tt) {
    if (tt + 1 < NT) stageK(tt + 1, Kbuf[(tt + 1) & 1]);
    f32x4 sacc[2][4] = {};
#pragma unroll
    for (int kk = 0; kk < 2; ++kk) {
      short8 kf[2];
#pragma unroll
      for (int tf = 0; tf < 2; ++tf) {
        int row = wid*32 + tf*16 + llo;
        kf[tf] = *(const short8*)((const char*)Kbuf[tt & 1] + row*128 + ((kk*64 + lhi*16) ^ ((row & 7) << 4)));
      }
#pragma unroll
      for (int tf = 0; tf < 2; ++tf)
#pragma unroll
        for (int qf = 0; qf < 4; ++qf)
          sacc[tf][qf] = __builtin_amdgcn_mfma_f32_16x16x32_bf16(kf[tf], qfr[qf][kk], sacc[tf][qf], 0, 0, 0);
    }
#pragma unroll
    for (int tf = 0; tf < 2; ++tf)
#pragma unroll
      for (int qf = 0; qf < 4; ++qf)
#pragma unroll
        for (int r = 0; r < 4; ++r)
          part[qf] += __expf(sacc[tf][qf][r]);
    wait_vm0(); bar_lgkm();
  }

  // wave-local reduce over lhi groups, then cross-wave via LDS
#pragma unroll
  for (int qf = 0; qf < 4; ++qf) {
    float v = part[qf];
    v += __shfl_xor(v, 16);
    v += __shfl_xor(v, 32);
    if (lhi == 0) lsum[wid][qf*16 + llo] = v;
  }
  stageK(0, Kbuf[0]);                         // K0 for pass 2
  bar_lgkm();                                 // lsum visible
  if (tid < QB) linv[tid] = 1.0f / (lsum[0][tid] + lsum[1][tid] + lsum[2][tid] + lsum[3][tid]);
  stageV(0);                                  // V0
  stageK(1, Kbuf[1]);                         // K1
  asm volatile("s_waitcnt vmcnt(8)" ::: "memory");   // own K0 done (V0+K1 = 8 newer)
  bar_lgkm();                                 // linv visible
  float lr[4];
#pragma unroll
  for (int qf = 0; qf < 4; ++qf) lr[qf] = linv[qf*16 + llo];

  // ---------------- pass 2: probs + PV (counted vmcnt, nt stores) ----------------
  f32x4 pv[4] = {};
  for (int tt = 0; tt < NT; ++tt) {
    // A: scores from Kbuf[tt&1]
    f32x4 sacc[2][4] = {};
#pragma unroll
    for (int kk = 0; kk < 2; ++kk) {
      short8 kf[2];
#pragma unroll
      for (int tf = 0; tf < 2; ++tf) {
        int row = wid*32 + tf*16 + llo;
        kf[tf] = *(const short8*)((const char*)Kbuf[tt & 1] + row*128 + ((kk*64 + lhi*16) ^ ((row & 7) << 4)));
      }
#pragma unroll
      for (int tf = 0; tf < 2; ++tf)
#pragma unroll
        for (int qf = 0; qf < 4; ++qf)
          sacc[tf][qf] = __builtin_amdgcn_mfma_f32_16x16x32_bf16(kf[tf], qfr[qf][kk], sacc[tf][qf], 0, 0, 0);
    }
    // B: exp, normalize, pack Ps (b64), stash probs values (f32x4 for nt store)
    f32x4 pst[2][4];
#pragma unroll
    for (int tf = 0; tf < 2; ++tf)
#pragma unroll
      for (int qf = 0; qf < 4; ++qf) {
        float p0 = __expf(sacc[tf][qf][0]) * lr[qf];
        float p1 = __expf(sacc[tf][qf][1]) * lr[qf];
        float p2 = __expf(sacc[tf][qf][2]) * lr[qf];
        float p3 = __expf(sacc[tf][qf][3]) * lr[qf];
        int q = qf*16 + llo;
        int t0 = wid*32 + tf*16 + lhi*4;
        uint2 w2; w2.x = pk2(p0, p1); w2.y = pk2(p2, p3);
        *(uint2*)((char*)Ps + q*256 + ((t0*2) ^ ((q & 7) << 4))) = w2;
        f32x4 pv4; pv4[0] = 8.f*p0; pv4[1] = 8.f*p1; pv4[2] = 8.f*p2; pv4[3] = 8.f*p3;
        pst[tf][qf] = pv4;
      }
    // B1: own V(tt) landed (stores/K may fly), then barrier
    if (tt == 0) asm volatile("s_waitcnt vmcnt(4) lgkmcnt(0)\n\ts_barrier" ::: "memory");
    else         asm volatile("s_waitcnt vmcnt(12) lgkmcnt(0)\n\ts_barrier" ::: "memory");
    // D: PV (reads Ps + Vs)
#pragma unroll
    for (int kk2 = 0; kk2 < 4; ++kk2) {
      int rq = wid*16 + llo;
      short8 pb = *(const short8*)((const char*)Ps + rq*256 + ((kk2*64 + lhi*16) ^ ((rq & 7) << 4)));
#pragma unroll
      for (int mf = 0; mf < 4; ++mf) {
        int rd = mf*16 + llo;
        short8 va = *(const short8*)((const char*)Vs + rd*256 + ((kk2*64 + lhi*16) ^ ((rd & 7) << 4)));
        pv[mf] = __builtin_amdgcn_mfma_f32_16x16x32_bf16(va, pb, pv[mf], 0, 0, 0);
      }
    }
    // B2: own K(tt+1) landed (stores may fly), then barrier
    if (tt == 0) asm volatile("s_waitcnt vmcnt(0)\n\ts_barrier" ::: "memory");
    else         asm volatile("s_waitcnt vmcnt(8)\n\ts_barrier" ::: "memory");
    // F: issue next-tile loads FIRST, then stores (order pinned by fences)
    stageV((tt + 1) & 15);                        // dummy wrap at tt=15 (never read)
    asm volatile("" ::: "memory");
    stageK((tt + 2) & 15, Kbuf[tt & 1]);          // dummy wrap at tt>=14 (never read)
    asm volatile("" ::: "memory");
#pragma unroll
    for (int tf = 0; tf < 2; ++tf)
#pragma unroll
      for (int qf = 0; qf < 4; ++qf) {
        int q = qf*16 + llo;
        int t0 = wid*32 + tf*16 + lhi*4;
        f32x4* dst = (f32x4*)&probs[((size_t)bh*T + q0 + q)*T + tt*TB + t0];
        __builtin_nontemporal_store(pst[tf][qf], dst);
      }
  }

  // attn out: D[d][q], lane has 4 consecutive d at q = wid*16+llo
#pragma unroll
  for (int mf = 0; mf < 4; ++mf) {
    int q = wid*16 + llo;
    int d0 = mf*16 + lhi*4;
    ushort4 o;
    o.x = f2b(pv[mf][0]); o.y = f2b(pv[mf][1]);
    o.z = f2b(pv[mf][2]); o.w = f2b(pv[mf][3]);
    *(ushort4*)(attnb + (tokQ + q)*1024 + h*64 + d0) = o;
  }
}

extern "C" void kernel_launch(void* const* d_in, const int* in_sizes, int n_in,
                              void* d_out, int out_size, void* d_ws, size_t ws_size,
                              hipStream_t stream) {
  (void)in_sizes; (void)n_in; (void)out_size; (void)ws_size;
  const float* x    = (const float*)d_in[0];
  const float* wqkv = (const float*)d_in[1];
  const float* bqkv = (const float*)d_in[2];
  const float* wout = (const float*)d_in[3];
  const float* bout = (const float*)d_in[4];

  constexpr int T = 2048, E = 1024;
  constexpr int M = 4 * T;
  constexpr size_t NX   = (size_t)M * E;
  constexpr size_t NW1  = (size_t)3 * E * E;
  constexpr size_t NW2  = (size_t)E * E;
  constexpr size_t NQK  = (size_t)M * 2048;
  constexpr size_t NVT  = (size_t)64 * 64 * T;

  char* ws = (char*)d_ws;
  unsigned short* xb    = (unsigned short*)ws;  ws += NX  * 2;
  unsigned short* wqkvb = (unsigned short*)ws;  ws += NW1 * 2;
  unsigned short* woutb = (unsigned short*)ws;  ws += NW2 * 2;
  unsigned short* qkb   = (unsigned short*)ws;  ws += NQK * 2;
  unsigned short* vtg   = (unsigned short*)ws;  ws += NVT * 2;
  unsigned short* attnb = (unsigned short*)ws;  ws += NX  * 2;

  cvt_f32_bf16<<<(int)(NX  / 1024), 256, 0, stream>>>(x,    xb,    (int)NX);
  cvt_f32_bf16<<<(int)(NW1 / 1024), 256, 0, stream>>>(wqkv, wqkvb, (int)NW1);
  cvt_f32_bf16<<<(int)(NW2 / 1024), 256, 0, stream>>>(wout, woutb, (int)NW2);

  gemm_bt<1><<<dim3(3*E/128, M/128), 256, 0, stream>>>(
      xb, wqkvb, bqkv, nullptr, qkb, vtg, 3*E, E);

  float* probsOut = (float*)d_out + NX;
  mha_fused<<<4*16*(T/64), 256, 0, stream>>>(qkb, vtg, probsOut, attnb);

  gemm_bt<0><<<dim3(E/128, M/128), 256, 0, stream>>>(
      attnb, woutb, bout, (float*)d_out, nullptr, nullptr, E, E);
}

// Round 9
// 419.751 us; speedup vs baseline: 1.7046x; 1.0149x over previous
//
#include <hip/hip_runtime.h>

// MHA forward, MI355X/gfx950 — round 9 (= R8 with the TRANS-hazard fix).
// R8 failed correctness: inline-asm v_exp_f32 output consumed by VALU without
// the required CDNA trans-op wait state (compiler can't see into asm) ->
// stale-register reads -> garbage denominators. Fix: __builtin_amdgcn_exp2f
// (compiler-known TRANS op, hazard handled). Everything else = R8:
//   - pass-1 barrier-free (wave-private K staging, per-wave vmcnt(4))
//   - exp -> exp2 with log2e folded into Q pre-scale
//   - XCD swizzle, pass-2 counted vmcnt, nontemporal probs/out stores

#define DEV __device__ __forceinline__

typedef __attribute__((ext_vector_type(8))) short short8;   // 8 bf16 (MFMA A/B frag)
typedef __attribute__((ext_vector_type(4))) float f32x4;    // MFMA C/D frag

DEV unsigned short f2b(float f) {   // f32 -> bf16 RNE
  union { float f; unsigned u; } v; v.f = f;
  unsigned r = v.u + 0x7fffu + ((v.u >> 16) & 1u);
  return (unsigned short)(r >> 16);
}
DEV unsigned pk2(float lo, float hi) {  // two f32 -> packed bf16x2
  return (unsigned)f2b(lo) | ((unsigned)f2b(hi) << 16);
}
#if __has_builtin(__builtin_amdgcn_exp2f)
DEV float exp2_fast(float x) { return __builtin_amdgcn_exp2f(x); }
#else
DEV float exp2_fast(float x) { return exp2f(x); }
#endif
DEV void gl_lds16(const void* g, void* l) {  // async global->LDS, dest = base + lane*16
  __builtin_amdgcn_global_load_lds(
      (const __attribute__((address_space(1))) void*)g,
      (__attribute__((address_space(3))) void*)l, 16, 0, 0);
}
DEV void bar_lgkm() { asm volatile("s_waitcnt lgkmcnt(0)\n\ts_barrier" ::: "memory"); }

__global__ void cvt_f32_bf16(const float* __restrict__ src, unsigned short* __restrict__ dst, int n) {
  int i = (blockIdx.x * blockDim.x + threadIdx.x) * 4;
  if (i >= n) return;
  float4 v = *(const float4*)(src + i);
  ushort4 o; o.x = f2b(v.x); o.y = f2b(v.y); o.z = f2b(v.z); o.w = f2b(v.w);
  *(ushort4*)(dst + i) = o;
}

// C = A @ B^T + bias; A[M][K], B[N][K] bf16. 128x128 tile, BK=64, 4 waves (2x2).
// MODE 0: fp32 C (ld=N, nontemporal).  MODE 1: QKV special — n<2048 -> bf16 Cqk
// (ld 2048, q cols scaled 0.125*log2e); n>=2048 -> V transposed into Vtg[bh][d][t].
template<int MODE>
__global__ __launch_bounds__(256, 2) void gemm_bt(
    const unsigned short* __restrict__ A,
    const unsigned short* __restrict__ B,
    const float* __restrict__ bias,
    float* __restrict__ Cf,
    unsigned short* __restrict__ Cqk,
    unsigned short* __restrict__ Vtg,
    int N, int K)
{
  constexpr int BK = 64;
  __shared__ __align__(16) unsigned short As[128*BK];
  __shared__ __align__(16) unsigned short Bs[128*BK];
  const int tid = threadIdx.x, lane = tid & 63, wid = tid >> 6;
  const int lhi = lane >> 4, llo = lane & 15;
  const int m0 = blockIdx.y * 128, n0 = blockIdx.x * 128;
  const int wr = wid >> 1, wc = wid & 1;

  f32x4 acc[4][4] = {};

  const int nsteps = K / BK;
  for (int kt = 0; kt < nsteps; ++kt) {
    __syncthreads();
#pragma unroll
    for (int s = 0; s < 4; ++s) {
      int u = wid*4 + s;
      int a = u*1024 + lane*16;
      int t = a >> 7;
      int cb = (a & 127) ^ ((t & 7) << 4);
      int e = kt*BK + (cb >> 1);
      gl_lds16(A + (size_t)(m0 + t)*K + e, (char*)As + u*1024);
      gl_lds16(B + (size_t)(n0 + t)*K + e, (char*)Bs + u*1024);
    }
    __syncthreads();
#pragma unroll
    for (int kk = 0; kk < 2; ++kk) {
      short8 af[4], bfr[4];
#pragma unroll
      for (int mf = 0; mf < 4; ++mf) {
        int row = wr*64 + mf*16 + llo;
        af[mf] = *(const short8*)((const char*)As + row*128 + ((kk*64 + lhi*16) ^ ((row & 7) << 4)));
      }
#pragma unroll
      for (int nf = 0; nf < 4; ++nf) {
        int row = wc*64 + nf*16 + llo;
        bfr[nf] = *(const short8*)((const char*)Bs + row*128 + ((kk*64 + lhi*16) ^ ((row & 7) << 4)));
      }
#pragma unroll
      for (int mf = 0; mf < 4; ++mf)
#pragma unroll
        for (int nf = 0; nf < 4; ++nf)
          acc[mf][nf] = __builtin_amdgcn_mfma_f32_16x16x32_bf16(af[mf], bfr[nf], acc[mf][nf], 0, 0, 0);
    }
  }
  // epilogue (C/D: row = lhi*4+r, col = llo)
  if (MODE == 0) {
#pragma unroll
    for (int mf = 0; mf < 4; ++mf)
#pragma unroll
      for (int nf = 0; nf < 4; ++nf) {
        int n = n0 + wc*64 + nf*16 + llo;
        float bv = bias[n];
#pragma unroll
        for (int r = 0; r < 4; ++r) {
          int m = m0 + wr*64 + mf*16 + lhi*4 + r;
          __builtin_nontemporal_store(acc[mf][nf][r] + bv, &Cf[(size_t)m*N + n]);
        }
      }
  } else {
    if (n0 < 2048) {  // Q/K region
#pragma unroll
      for (int mf = 0; mf < 4; ++mf)
#pragma unroll
        for (int nf = 0; nf < 4; ++nf) {
          int n = n0 + wc*64 + nf*16 + llo;
          float bv = bias[n];
          // q pre-scale folds softmax scale AND log2e (exp -> exp2)
          float sc = (n < 1024) ? 0.125f * 1.44269504088896f : 1.0f;
#pragma unroll
          for (int r = 0; r < 4; ++r) {
            int m = m0 + wr*64 + mf*16 + lhi*4 + r;
            Cqk[(size_t)m*2048 + n] = f2b((acc[mf][nf][r] + bv) * sc);
          }
        }
    } else {          // V region -> transposed Vtg[bh][d][t]
#pragma unroll
      for (int mf = 0; mf < 4; ++mf)
#pragma unroll
        for (int nf = 0; nf < 4; ++nf) {
          int n = n0 + wc*64 + nf*16 + llo;
          float bv = bias[n];
          int hh = (n - 2048) >> 6, d = (n - 2048) & 63;
          int m = m0 + wr*64 + mf*16 + lhi*4;
          int bb = m >> 11, t = m & 2047;
          ushort4 o;
          o.x = f2b(acc[mf][nf][0] + bv);
          o.y = f2b(acc[mf][nf][1] + bv);
          o.z = f2b(acc[mf][nf][2] + bv);
          o.w = f2b(acc[mf][nf][3] + bv);
          *(ushort4*)(Vtg + ((size_t)((bb << 4) + hh)*64 + d)*2048 + t) = o;
        }
    }
  }
}

// Fused attention. Block = (b,h,qt): 64 q-rows, 4 waves. Wave w owns t-cols
// [w*32,w*32+32) for scores (mfma(K,Q): D[t][q]) and q-rows [w*16,w*16+16)
// for PV (mfma(Vt,P): D[d][q]). K staging is wave-private (wave w stages the
// rows it reads) -> pass 1 needs no barriers at all.
__global__ __launch_bounds__(256, 2) void mha_fused(
    const unsigned short* __restrict__ qk,    // [8192][2048] bf16 (q scaled)
    const unsigned short* __restrict__ vtg,   // [64 bh][64 d][2048 t] bf16
    float* __restrict__ probs,                // [64 bh][2048][2048] f32
    unsigned short* __restrict__ attnb)       // [8192][1024] bf16
{
  constexpr int T = 2048, LD = 2048, QB = 64, TB = 128, NT = T / TB;
  __shared__ __align__(16) unsigned short Qs[QB*64];        //  8 KB
  __shared__ __align__(16) unsigned short Kbuf[2][TB*64];   // 32 KB
  __shared__ __align__(16) unsigned short Vs[64*TB];        // 16 KB
  __shared__ __align__(16) unsigned short Ps[QB*TB];        // 16 KB
  __shared__ float lsum[4][QB];
  __shared__ float linv[QB];

  const int tid = threadIdx.x, lane = tid & 63, wid = tid >> 6;
  const int lhi = lane >> 4, llo = lane & 15;
  // XCD swizzle (T1): wgid = (bid%8)*256 + bid/8 (bijective, 2048%8==0).
  const int wg = ((blockIdx.x & 7) << 8) | (blockIdx.x >> 3);
  const int qt = wg & 31, bh = wg >> 5;
  const int bb = bh >> 4, h = bh & 15;
  const int q0 = qt * QB;
  const size_t tokQ = (size_t)bb*T + q0;

  auto stageK = [&](int tt, unsigned short* buf) {
#pragma unroll
    for (int s = 0; s < 4; ++s) {
      int u = wid*4 + s;
      int a = u*1024 + lane*16;
      int tr = a >> 7;
      int cb = (a & 127) ^ ((tr & 7) << 4);
      gl_lds16(qk + ((size_t)bb*T + tt*TB + tr)*LD + 1024 + h*64 + (cb >> 1),
               (char*)buf + u*1024);
    }
  };
  auto stageV = [&](int tt) {
#pragma unroll
    for (int s = 0; s < 4; ++s) {
      int u = wid*4 + s;
      int a = u*1024 + lane*16;
      int d = a >> 8;
      int cb = (a & 255) ^ ((d & 7) << 4);
      gl_lds16(vtg + ((size_t)bh*64 + d)*T + tt*TB + (cb >> 1),
               (char*)Vs + u*1024);
    }
  };

  // ---- prologue: Q (2 loads/wave) + K0; wait own Q, publish ----
#pragma unroll
  for (int s = 0; s < 2; ++s) {
    int u = wid*2 + s;
    int a = u*1024 + lane*16;
    int tr = a >> 7;
    int cb = (a & 127) ^ ((tr & 7) << 4);
    gl_lds16(qk + (tokQ + tr)*LD + h*64 + (cb >> 1), (char*)Qs + u*1024);
  }
  stageK(0, Kbuf[0]);
  asm volatile("s_waitcnt vmcnt(4)" ::: "memory");   // Q done (K0 in flight)
  __builtin_amdgcn_s_barrier();                      // publish Q

  // Q fragments in registers (loop-invariant)
  short8 qfr[4][2];
#pragma unroll
  for (int qf = 0; qf < 4; ++qf)
#pragma unroll
    for (int kk = 0; kk < 2; ++kk) {
      int row = qf*16 + llo;
      qfr[qf][kk] = *(const short8*)((const char*)Qs + row*128 + ((kk*64 + lhi*16) ^ ((row & 7) << 4)));
    }

  // ---------------- pass 1: denominators (no barriers) ----------------
  float part[4] = {0.f, 0.f, 0.f, 0.f};
  for (int tt = 0; tt < NT; ++tt) {
    stageK((tt + 1) & 15, Kbuf[(tt + 1) & 1]);       // dummy at 15 -> K0 into buf0
    asm volatile("s_waitcnt vmcnt(4)" ::: "memory"); // own K(tt) landed
    f32x4 sacc[2][4] = {};
#pragma unroll
    for (int kk = 0; kk < 2; ++kk) {
      short8 kf[2];
#pragma unroll
      for (int tf = 0; tf < 2; ++tf) {
        int row = wid*32 + tf*16 + llo;
        kf[tf] = *(const short8*)((const char*)Kbuf[tt & 1] + row*128 + ((kk*64 + lhi*16) ^ ((row & 7) << 4)));
      }
#pragma unroll
      for (int tf = 0; tf < 2; ++tf)
#pragma unroll
        for (int qf = 0; qf < 4; ++qf)
          sacc[tf][qf] = __builtin_amdgcn_mfma_f32_16x16x32_bf16(kf[tf], qfr[qf][kk], sacc[tf][qf], 0, 0, 0);
    }
#pragma unroll
    for (int tf = 0; tf < 2; ++tf)
#pragma unroll
      for (int qf = 0; qf < 4; ++qf)
#pragma unroll
        for (int r = 0; r < 4; ++r)
          part[qf] += exp2_fast(sacc[tf][qf][r]);
  }

  // wave-local reduce over lhi groups, then cross-wave via LDS
#pragma unroll
  for (int qf = 0; qf < 4; ++qf) {
    float v = part[qf];
    v += __shfl_xor(v, 16);
    v += __shfl_xor(v, 32);
    if (lhi == 0) lsum[wid][qf*16 + llo] = v;
  }
  bar_lgkm();                                 // lsum visible
  if (tid < QB) linv[tid] = 1.0f / (lsum[0][tid] + lsum[1][tid] + lsum[2][tid] + lsum[3][tid]);
  stageV(0);                                  // V0
  stageK(1, Kbuf[1]);                         // K1
  asm volatile("s_waitcnt vmcnt(8)" ::: "memory");   // dummy-K0 done; V0+K1 in flight
  bar_lgkm();                                 // linv published
  float lr[4];
#pragma unroll
  for (int qf = 0; qf < 4; ++qf) lr[qf] = linv[qf*16 + llo];

  // ---------------- pass 2: probs + PV (counted vmcnt, nt stores) ----------------
  f32x4 pv[4] = {};
  for (int tt = 0; tt < NT; ++tt) {
    // A: scores from Kbuf[tt&1]
    f32x4 sacc[2][4] = {};
#pragma unroll
    for (int kk = 0; kk < 2; ++kk) {
      short8 kf[2];
#pragma unroll
      for (int tf = 0; tf < 2; ++tf) {
        int row = wid*32 + tf*16 + llo;
        kf[tf] = *(const short8*)((const char*)Kbuf[tt & 1] + row*128 + ((kk*64 + lhi*16) ^ ((row & 7) << 4)));
      }
#pragma unroll
      for (int tf = 0; tf < 2; ++tf)
#pragma unroll
        for (int qf = 0; qf < 4; ++qf)
          sacc[tf][qf] = __builtin_amdgcn_mfma_f32_16x16x32_bf16(kf[tf], qfr[qf][kk], sacc[tf][qf], 0, 0, 0);
    }
    // B: exp2, normalize, pack Ps (b64), stash probs values (f32x4 for nt store)
    f32x4 pst[2][4];
#pragma unroll
    for (int tf = 0; tf < 2; ++tf)
#pragma unroll
      for (int qf = 0; qf < 4; ++qf) {
        float p0 = exp2_fast(sacc[tf][qf][0]) * lr[qf];
        float p1 = exp2_fast(sacc[tf][qf][1]) * lr[qf];
        float p2 = exp2_fast(sacc[tf][qf][2]) * lr[qf];
        float p3 = exp2_fast(sacc[tf][qf][3]) * lr[qf];
        int q = qf*16 + llo;
        int t0 = wid*32 + tf*16 + lhi*4;
        uint2 w2; w2.x = pk2(p0, p1); w2.y = pk2(p2, p3);
        *(uint2*)((char*)Ps + q*256 + ((t0*2) ^ ((q & 7) << 4))) = w2;
        f32x4 pv4; pv4[0] = 8.f*p0; pv4[1] = 8.f*p1; pv4[2] = 8.f*p2; pv4[3] = 8.f*p3;
        pst[tf][qf] = pv4;
      }
    // B1: own V(tt) landed (stores/K may fly), then barrier
    if (tt == 0) asm volatile("s_waitcnt vmcnt(4) lgkmcnt(0)\n\ts_barrier" ::: "memory");
    else         asm volatile("s_waitcnt vmcnt(12) lgkmcnt(0)\n\ts_barrier" ::: "memory");
    // D: PV (reads Ps + Vs)
#pragma unroll
    for (int kk2 = 0; kk2 < 4; ++kk2) {
      int rq = wid*16 + llo;
      short8 pb = *(const short8*)((const char*)Ps + rq*256 + ((kk2*64 + lhi*16) ^ ((rq & 7) << 4)));
#pragma unroll
      for (int mf = 0; mf < 4; ++mf) {
        int rd = mf*16 + llo;
        short8 va = *(const short8*)((const char*)Vs + rd*256 + ((kk2*64 + lhi*16) ^ ((rd & 7) << 4)));
        pv[mf] = __builtin_amdgcn_mfma_f32_16x16x32_bf16(va, pb, pv[mf], 0, 0, 0);
      }
    }
    // B2: own K(tt+1) landed (stores may fly), then barrier
    if (tt == 0) asm volatile("s_waitcnt vmcnt(0)\n\ts_barrier" ::: "memory");
    else         asm volatile("s_waitcnt vmcnt(8)\n\ts_barrier" ::: "memory");
    // F: issue next-tile loads FIRST, then stores (order pinned by fences)
    stageV((tt + 1) & 15);                        // dummy wrap at tt=15 (never read)
    asm volatile("" ::: "memory");
    stageK((tt + 2) & 15, Kbuf[tt & 1]);          // dummy wrap at tt>=14 (never read)
    asm volatile("" ::: "memory");
#pragma unroll
    for (int tf = 0; tf < 2; ++tf)
#pragma unroll
      for (int qf = 0; qf < 4; ++qf) {
        int q = qf*16 + llo;
        int t0 = wid*32 + tf*16 + lhi*4;
        f32x4* dst = (f32x4*)&probs[((size_t)bh*T + q0 + q)*T + tt*TB + t0];
        __builtin_nontemporal_store(pst[tf][qf], dst);
      }
  }

  // attn out: D[d][q], lane has 4 consecutive d at q = wid*16+llo
#pragma unroll
  for (int mf = 0; mf < 4; ++mf) {
    int q = wid*16 + llo;
    int d0 = mf*16 + lhi*4;
    ushort4 o;
    o.x = f2b(pv[mf][0]); o.y = f2b(pv[mf][1]);
    o.z = f2b(pv[mf][2]); o.w = f2b(pv[mf][3]);
    *(ushort4*)(attnb + (tokQ + q)*1024 + h*64 + d0) = o;
  }
}

extern "C" void kernel_launch(void* const* d_in, const int* in_sizes, int n_in,
                              void* d_out, int out_size, void* d_ws, size_t ws_size,
                              hipStream_t stream) {
  (void)in_sizes; (void)n_in; (void)out_size; (void)ws_size;
  const float* x    = (const float*)d_in[0];
  const float* wqkv = (const float*)d_in[1];
  const float* bqkv = (const float*)d_in[2];
  const float* wout = (const float*)d_in[3];
  const float* bout = (const float*)d_in[4];

  constexpr int T = 2048, E = 1024;
  constexpr int M = 4 * T;
  constexpr size_t NX   = (size_t)M * E;
  constexpr size_t NW1  = (size_t)3 * E * E;
  constexpr size_t NW2  = (size_t)E * E;
  constexpr size_t NQK  = (size_t)M * 2048;
  constexpr size_t NVT  = (size_t)64 * 64 * T;

  char* ws = (char*)d_ws;
  unsigned short* xb    = (unsigned short*)ws;  ws += NX  * 2;
  unsigned short* wqkvb = (unsigned short*)ws;  ws += NW1 * 2;
  unsigned short* woutb = (unsigned short*)ws;  ws += NW2 * 2;
  unsigned short* qkb   = (unsigned short*)ws;  ws += NQK * 2;
  unsigned short* vtg   = (unsigned short*)ws;  ws += NVT * 2;
  unsigned short* attnb = (unsigned short*)ws;  ws += NX  * 2;

  cvt_f32_bf16<<<(int)(NX  / 1024), 256, 0, stream>>>(x,    xb,    (int)NX);
  cvt_f32_bf16<<<(int)(NW1 / 1024), 256, 0, stream>>>(wqkv, wqkvb, (int)NW1);
  cvt_f32_bf16<<<(int)(NW2 / 1024), 256, 0, stream>>>(wout, woutb, (int)NW2);

  gemm_bt<1><<<dim3(3*E/128, M/128), 256, 0, stream>>>(
      xb, wqkvb, bqkv, nullptr, qkb, vtg, 3*E, E);

  float* probsOut = (float*)d_out + NX;
  mha_fused<<<4*16*(T/64), 256, 0, stream>>>(qkb, vtg, probsOut, attnb);

  gemm_bt<0><<<dim3(E/128, M/128), 256, 0, stream>>>(
      attnb, woutb, bout, (float*)d_out, nullptr, nullptr, E, E);
}

// Round 10
// 372.066 us; speedup vs baseline: 1.9230x; 1.1282x over previous
//
#include <hip/hip_runtime.h>

// MHA forward, MI355X/gfx950 — round 10.
// Change vs R9 (one bucket: attn occupancy + phase overlap):
//   - LDS 72.5 -> 49.5 KB => 3 blocks/CU (launch_bounds(256,3)): Qs aliased
//     into Ps (Q is in regs after prologue), pass-2 uses a SINGLE K buffer
//     (K rows are wave-private: a wave overwrites its own rows right after
//     its own scores — no barrier needed), pass-1 rings over Kslot/Vslot.
//   - Pass-2 probs stores issue directly in phase B (pst stash removed,
//     -32 VGPR). Uniform waits: iter-top vmcnt(12) guards own K(tt);
//     B1 vmcnt(12)+lgkmcnt(0)+barrier guards V(tt)+publishes Ps. Stores
//     always >=1 iter old before entering any drain set.
//   - stageK(tt+1) after scores behind lgkmcnt(0)+sched_barrier (rule #18).
// Kept: XCD swizzle, exp2 (builtin), nt stores, barrier-free pass 1, GEMMs.

#define DEV __device__ __forceinline__

typedef __attribute__((ext_vector_type(8))) short short8;   // 8 bf16 (MFMA A/B frag)
typedef __attribute__((ext_vector_type(4))) float f32x4;    // MFMA C/D frag

DEV unsigned short f2b(float f) {   // f32 -> bf16 RNE
  union { float f; unsigned u; } v; v.f = f;
  unsigned r = v.u + 0x7fffu + ((v.u >> 16) & 1u);
  return (unsigned short)(r >> 16);
}
DEV unsigned pk2(float lo, float hi) {  // two f32 -> packed bf16x2
  return (unsigned)f2b(lo) | ((unsigned)f2b(hi) << 16);
}
#if __has_builtin(__builtin_amdgcn_exp2f)
DEV float exp2_fast(float x) { return __builtin_amdgcn_exp2f(x); }
#else
DEV float exp2_fast(float x) { return exp2f(x); }
#endif
DEV void gl_lds16(const void* g, void* l) {  // async global->LDS, dest = base + lane*16
  __builtin_amdgcn_global_load_lds(
      (const __attribute__((address_space(1))) void*)g,
      (__attribute__((address_space(3))) void*)l, 16, 0, 0);
}
DEV void bar_lgkm() { asm volatile("s_waitcnt lgkmcnt(0)\n\ts_barrier" ::: "memory"); }

__global__ void cvt_f32_bf16(const float* __restrict__ src, unsigned short* __restrict__ dst, int n) {
  int i = (blockIdx.x * blockDim.x + threadIdx.x) * 4;
  if (i >= n) return;
  float4 v = *(const float4*)(src + i);
  ushort4 o; o.x = f2b(v.x); o.y = f2b(v.y); o.z = f2b(v.z); o.w = f2b(v.w);
  *(ushort4*)(dst + i) = o;
}

// C = A @ B^T + bias; A[M][K], B[N][K] bf16. 128x128 tile, BK=64, 4 waves (2x2).
// MODE 0: fp32 C (ld=N, nontemporal).  MODE 1: QKV special — n<2048 -> bf16 Cqk
// (ld 2048, q cols scaled 0.125*log2e); n>=2048 -> V transposed into Vtg[bh][d][t].
template<int MODE>
__global__ __launch_bounds__(256, 2) void gemm_bt(
    const unsigned short* __restrict__ A,
    const unsigned short* __restrict__ B,
    const float* __restrict__ bias,
    float* __restrict__ Cf,
    unsigned short* __restrict__ Cqk,
    unsigned short* __restrict__ Vtg,
    int N, int K)
{
  constexpr int BK = 64;
  __shared__ __align__(16) unsigned short As[128*BK];
  __shared__ __align__(16) unsigned short Bs[128*BK];
  const int tid = threadIdx.x, lane = tid & 63, wid = tid >> 6;
  const int lhi = lane >> 4, llo = lane & 15;
  const int m0 = blockIdx.y * 128, n0 = blockIdx.x * 128;
  const int wr = wid >> 1, wc = wid & 1;

  f32x4 acc[4][4] = {};

  const int nsteps = K / BK;
  for (int kt = 0; kt < nsteps; ++kt) {
    __syncthreads();
#pragma unroll
    for (int s = 0; s < 4; ++s) {
      int u = wid*4 + s;
      int a = u*1024 + lane*16;
      int t = a >> 7;
      int cb = (a & 127) ^ ((t & 7) << 4);
      int e = kt*BK + (cb >> 1);
      gl_lds16(A + (size_t)(m0 + t)*K + e, (char*)As + u*1024);
      gl_lds16(B + (size_t)(n0 + t)*K + e, (char*)Bs + u*1024);
    }
    __syncthreads();
#pragma unroll
    for (int kk = 0; kk < 2; ++kk) {
      short8 af[4], bfr[4];
#pragma unroll
      for (int mf = 0; mf < 4; ++mf) {
        int row = wr*64 + mf*16 + llo;
        af[mf] = *(const short8*)((const char*)As + row*128 + ((kk*64 + lhi*16) ^ ((row & 7) << 4)));
      }
#pragma unroll
      for (int nf = 0; nf < 4; ++nf) {
        int row = wc*64 + nf*16 + llo;
        bfr[nf] = *(const short8*)((const char*)Bs + row*128 + ((kk*64 + lhi*16) ^ ((row & 7) << 4)));
      }
#pragma unroll
      for (int mf = 0; mf < 4; ++mf)
#pragma unroll
        for (int nf = 0; nf < 4; ++nf)
          acc[mf][nf] = __builtin_amdgcn_mfma_f32_16x16x32_bf16(af[mf], bfr[nf], acc[mf][nf], 0, 0, 0);
    }
  }
  // epilogue (C/D: row = lhi*4+r, col = llo)
  if (MODE == 0) {
#pragma unroll
    for (int mf = 0; mf < 4; ++mf)
#pragma unroll
      for (int nf = 0; nf < 4; ++nf) {
        int n = n0 + wc*64 + nf*16 + llo;
        float bv = bias[n];
#pragma unroll
        for (int r = 0; r < 4; ++r) {
          int m = m0 + wr*64 + mf*16 + lhi*4 + r;
          __builtin_nontemporal_store(acc[mf][nf][r] + bv, &Cf[(size_t)m*N + n]);
        }
      }
  } else {
    if (n0 < 2048) {  // Q/K region
#pragma unroll
      for (int mf = 0; mf < 4; ++mf)
#pragma unroll
        for (int nf = 0; nf < 4; ++nf) {
          int n = n0 + wc*64 + nf*16 + llo;
          float bv = bias[n];
          // q pre-scale folds softmax scale AND log2e (exp -> exp2)
          float sc = (n < 1024) ? 0.125f * 1.44269504088896f : 1.0f;
#pragma unroll
          for (int r = 0; r < 4; ++r) {
            int m = m0 + wr*64 + mf*16 + lhi*4 + r;
            Cqk[(size_t)m*2048 + n] = f2b((acc[mf][nf][r] + bv) * sc);
          }
        }
    } else {          // V region -> transposed Vtg[bh][d][t]
#pragma unroll
      for (int mf = 0; mf < 4; ++mf)
#pragma unroll
        for (int nf = 0; nf < 4; ++nf) {
          int n = n0 + wc*64 + nf*16 + llo;
          float bv = bias[n];
          int hh = (n - 2048) >> 6, d = (n - 2048) & 63;
          int m = m0 + wr*64 + mf*16 + lhi*4;
          int bb = m >> 11, t = m & 2047;
          ushort4 o;
          o.x = f2b(acc[mf][nf][0] + bv);
          o.y = f2b(acc[mf][nf][1] + bv);
          o.z = f2b(acc[mf][nf][2] + bv);
          o.w = f2b(acc[mf][nf][3] + bv);
          *(ushort4*)(Vtg + ((size_t)((bb << 4) + hh)*64 + d)*2048 + t) = o;
        }
    }
  }
}

// Fused attention. Block = (b,h,qt): 64 q-rows, 4 waves, 3 blocks/CU.
// Wave w owns t-cols [w*32,w*32+32) for scores (mfma(K,Q): D[t][q]) and
// q-rows [w*16,w*16+16) for PV (mfma(Vt,P): D[d][q]).
// K rows in LDS are wave-private (wave w stages & reads rows [32w,32w+32)).
__global__ __launch_bounds__(256, 3) void mha_fused(
    const unsigned short* __restrict__ qk,    // [8192][2048] bf16 (q scaled)
    const unsigned short* __restrict__ vtg,   // [64 bh][64 d][2048 t] bf16
    float* __restrict__ probs,                // [64 bh][2048][2048] f32
    unsigned short* __restrict__ attnb)       // [8192][1024] bf16
{
  constexpr int T = 2048, LD = 2048, QB = 64, TB = 128, NT = T / TB;
  __shared__ __align__(16) unsigned short Kslot[TB*64];   // 16 KB (pass1 ring even; pass2 K)
  __shared__ __align__(16) unsigned short Vslot[64*TB];   // 16 KB (pass1 ring odd;  pass2 V)
  __shared__ __align__(16) unsigned short Ps[QB*TB];      // 16 KB (prologue: Q in first 8KB)
  __shared__ float lsum[4][QB];
  __shared__ float linv[QB];

  const int tid = threadIdx.x, lane = tid & 63, wid = tid >> 6;
  const int lhi = lane >> 4, llo = lane & 15;
  // XCD swizzle (T1): wgid = (bid%8)*256 + bid/8 (bijective, 2048%8==0).
  const int wg = ((blockIdx.x & 7) << 8) | (blockIdx.x >> 3);
  const int qt = wg & 31, bh = wg >> 5;
  const int bb = bh >> 4, h = bh & 15;
  const int q0 = qt * QB;
  const size_t tokQ = (size_t)bb*T + q0;

  auto stageK = [&](int tt, unsigned short* buf) {
#pragma unroll
    for (int s = 0; s < 4; ++s) {
      int u = wid*4 + s;
      int a = u*1024 + lane*16;
      int tr = a >> 7;
      int cb = (a & 127) ^ ((tr & 7) << 4);
      gl_lds16(qk + ((size_t)bb*T + tt*TB + tr)*LD + 1024 + h*64 + (cb >> 1),
               (char*)buf + u*1024);
    }
  };
  auto stageV = [&](int tt) {
#pragma unroll
    for (int s = 0; s < 4; ++s) {
      int u = wid*4 + s;
      int a = u*1024 + lane*16;
      int d = a >> 8;
      int cb = (a & 255) ^ ((d & 7) << 4);
      gl_lds16(vtg + ((size_t)bh*64 + d)*T + tt*TB + (cb >> 1),
               (char*)Vslot + u*1024);
    }
  };

  // ---- prologue: Q (into Ps region, 2 loads/wave) + K0 ----
#pragma unroll
  for (int s = 0; s < 2; ++s) {
    int u = wid*2 + s;
    int a = u*1024 + lane*16;
    int tr = a >> 7;
    int cb = (a & 127) ^ ((tr & 7) << 4);
    gl_lds16(qk + (tokQ + tr)*LD + h*64 + (cb >> 1), (char*)Ps + u*1024);
  }
  stageK(0, Kslot);
  asm volatile("s_waitcnt vmcnt(4)" ::: "memory");   // own Q done (K0 in flight)
  __builtin_amdgcn_s_barrier();                      // publish Q

  // Q fragments in registers (loop-invariant)
  short8 qfr[4][2];
#pragma unroll
  for (int qf = 0; qf < 4; ++qf)
#pragma unroll
    for (int kk = 0; kk < 2; ++kk) {
      int row = qf*16 + llo;
      qfr[qf][kk] = *(const short8*)((const char*)Ps + row*128 + ((kk*64 + lhi*16) ^ ((row & 7) << 4)));
    }

  // ---------------- pass 1: denominators (no barriers; ring Kslot/Vslot) ----------------
  float part[4] = {0.f, 0.f, 0.f, 0.f};
  for (int tt = 0; tt < NT; ++tt) {
    unsigned short* nxt = ((tt + 1) & 1) ? Vslot : Kslot;
    stageK((tt + 1) & 15, nxt);                      // tt=15 stages real K0 for pass 2
    asm volatile("s_waitcnt vmcnt(4)" ::: "memory"); // own K(tt) landed
    const unsigned short* cur = (tt & 1) ? Vslot : Kslot;
    f32x4 sacc[2][4] = {};
#pragma unroll
    for (int kk = 0; kk < 2; ++kk) {
      short8 kf[2];
#pragma unroll
      for (int tf = 0; tf < 2; ++tf) {
        int row = wid*32 + tf*16 + llo;
        kf[tf] = *(const short8*)((const char*)cur + row*128 + ((kk*64 + lhi*16) ^ ((row & 7) << 4)));
      }
#pragma unroll
      for (int tf = 0; tf < 2; ++tf)
#pragma unroll
        for (int qf = 0; qf < 4; ++qf)
          sacc[tf][qf] = __builtin_amdgcn_mfma_f32_16x16x32_bf16(kf[tf], qfr[qf][kk], sacc[tf][qf], 0, 0, 0);
    }
#pragma unroll
    for (int tf = 0; tf < 2; ++tf)
#pragma unroll
      for (int qf = 0; qf < 4; ++qf)
#pragma unroll
        for (int r = 0; r < 4; ++r)
          part[qf] += exp2_fast(sacc[tf][qf][r]);
  }

  // reduce: wave-local over lhi groups, then cross-wave via LDS
#pragma unroll
  for (int qf = 0; qf < 4; ++qf) {
    float v = part[qf];
    v += __shfl_xor(v, 16);
    v += __shfl_xor(v, 32);
    if (lhi == 0) lsum[wid][qf*16 + llo] = v;
  }
  bar_lgkm();                                 // lsum visible (also: all waves past pass 1)
  if (tid < QB) linv[tid] = 1.0f / (lsum[0][tid] + lsum[1][tid] + lsum[2][tid] + lsum[3][tid]);
  stageV(0);                                  // V0 into Vslot (safe: all past pass 1)
  bar_lgkm();                                 // linv visible
  float lr[4];
#pragma unroll
  for (int qf = 0; qf < 4; ++qf) lr[qf] = linv[qf*16 + llo];

  // ---------------- pass 2: probs + PV (single K buffer, uniform vmcnt(12)) ----------------
  f32x4 pv[4] = {};
  for (int tt = 0; tt < NT; ++tt) {
    // top: own K(tt) landed. Steady state keeps stores(tt-1)8 + V(tt)4 = 12.
    if (tt == 0) asm volatile("s_waitcnt vmcnt(4)"  ::: "memory");
    else         asm volatile("s_waitcnt vmcnt(12)" ::: "memory");
    // A: scores from own Kslot rows
    f32x4 sacc[2][4] = {};
#pragma unroll
    for (int kk = 0; kk < 2; ++kk) {
      short8 kf[2];
#pragma unroll
      for (int tf = 0; tf < 2; ++tf) {
        int row = wid*32 + tf*16 + llo;
        kf[tf] = *(const short8*)((const char*)Kslot + row*128 + ((kk*64 + lhi*16) ^ ((row & 7) << 4)));
      }
#pragma unroll
      for (int tf = 0; tf < 2; ++tf)
#pragma unroll
        for (int qf = 0; qf < 4; ++qf)
          sacc[tf][qf] = __builtin_amdgcn_mfma_f32_16x16x32_bf16(kf[tf], qfr[qf][kk], sacc[tf][qf], 0, 0, 0);
    }
    // own ds_reads complete, then overwrite own K rows with K(tt+1)
    asm volatile("s_waitcnt lgkmcnt(0)" ::: "memory");
    __builtin_amdgcn_sched_barrier(0);
    stageK((tt + 1) & 15, Kslot);                    // dummy wrap at tt=15
    // B: exp2, normalize, pack Ps (b64 ds), nt-store probs directly
#pragma unroll
    for (int tf = 0; tf < 2; ++tf)
#pragma unroll
      for (int qf = 0; qf < 4; ++qf) {
        float p0 = exp2_fast(sacc[tf][qf][0]) * lr[qf];
        float p1 = exp2_fast(sacc[tf][qf][1]) * lr[qf];
        float p2 = exp2_fast(sacc[tf][qf][2]) * lr[qf];
        float p3 = exp2_fast(sacc[tf][qf][3]) * lr[qf];
        int q = qf*16 + llo;
        int t0 = wid*32 + tf*16 + lhi*4;
        uint2 w2; w2.x = pk2(p0, p1); w2.y = pk2(p2, p3);
        *(uint2*)((char*)Ps + q*256 + ((t0*2) ^ ((q & 7) << 4))) = w2;
        f32x4 pv4; pv4[0] = 8.f*p0; pv4[1] = 8.f*p1; pv4[2] = 8.f*p2; pv4[3] = 8.f*p3;
        __builtin_nontemporal_store(pv4,
            (f32x4*)&probs[((size_t)bh*T + q0 + q)*T + tt*TB + t0]);
      }
    // B1: V(tt) landed (keep K(tt+1)4 + stores(tt)8 = 12), publish Ps
    asm volatile("s_waitcnt vmcnt(12) lgkmcnt(0)\n\ts_barrier" ::: "memory");
    // D: PV (reads Ps + Vslot)
#pragma unroll
    for (int kk2 = 0; kk2 < 4; ++kk2) {
      int rq = wid*16 + llo;
      short8 pb = *(const short8*)((const char*)Ps + rq*256 + ((kk2*64 + lhi*16) ^ ((rq & 7) << 4)));
#pragma unroll
      for (int mf = 0; mf < 4; ++mf) {
        int rd = mf*16 + llo;
        short8 va = *(const short8*)((const char*)Vslot + rd*256 + ((kk2*64 + lhi*16) ^ ((rd & 7) << 4)));
        pv[mf] = __builtin_amdgcn_mfma_f32_16x16x32_bf16(va, pb, pv[mf], 0, 0, 0);
      }
    }
    // B2: all waves done with Ps/Vslot before overwrite next iter
    asm volatile("s_waitcnt lgkmcnt(0)\n\ts_barrier" ::: "memory");
    // F: issue next V
    stageV((tt + 1) & 15);                           // dummy wrap at tt=15
  }

  // attn out: D[d][q], lane has 4 consecutive d at q = wid*16+llo
#pragma unroll
  for (int mf = 0; mf < 4; ++mf) {
    int q = wid*16 + llo;
    int d0 = mf*16 + lhi*4;
    ushort4 o;
    o.x = f2b(pv[mf][0]); o.y = f2b(pv[mf][1]);
    o.z = f2b(pv[mf][2]); o.w = f2b(pv[mf][3]);
    *(ushort4*)(attnb + (tokQ + q)*1024 + h*64 + d0) = o;
  }
}

extern "C" void kernel_launch(void* const* d_in, const int* in_sizes, int n_in,
                              void* d_out, int out_size, void* d_ws, size_t ws_size,
                              hipStream_t stream) {
  (void)in_sizes; (void)n_in; (void)out_size; (void)ws_size;
  const float* x    = (const float*)d_in[0];
  const float* wqkv = (const float*)d_in[1];
  const float* bqkv = (const float*)d_in[2];
  const float* wout = (const float*)d_in[3];
  const float* bout = (const float*)d_in[4];

  constexpr int T = 2048, E = 1024;
  constexpr int M = 4 * T;
  constexpr size_t NX   = (size_t)M * E;
  constexpr size_t NW1  = (size_t)3 * E * E;
  constexpr size_t NW2  = (size_t)E * E;
  constexpr size_t NQK  = (size_t)M * 2048;
  constexpr size_t NVT  = (size_t)64 * 64 * T;

  char* ws = (char*)d_ws;
  unsigned short* xb    = (unsigned short*)ws;  ws += NX  * 2;
  unsigned short* wqkvb = (unsigned short*)ws;  ws += NW1 * 2;
  unsigned short* woutb = (unsigned short*)ws;  ws += NW2 * 2;
  unsigned short* qkb   = (unsigned short*)ws;  ws += NQK * 2;
  unsigned short* vtg   = (unsigned short*)ws;  ws += NVT * 2;
  unsigned short* attnb = (unsigned short*)ws;  ws += NX  * 2;

  cvt_f32_bf16<<<(int)(NX  / 1024), 256, 0, stream>>>(x,    xb,    (int)NX);
  cvt_f32_bf16<<<(int)(NW1 / 1024), 256, 0, stream>>>(wqkv, wqkvb, (int)NW1);
  cvt_f32_bf16<<<(int)(NW2 / 1024), 256, 0, stream>>>(wout, woutb, (int)NW2);

  gemm_bt<1><<<dim3(3*E/128, M/128), 256, 0, stream>>>(
      xb, wqkvb, bqkv, nullptr, qkb, vtg, 3*E, E);

  float* probsOut = (float*)d_out + NX;
  mha_fused<<<4*16*(T/64), 256, 0, stream>>>(qkb, vtg, probsOut, attnb);

  gemm_bt<0><<<dim3(E/128, M/128), 256, 0, stream>>>(
      attnb, woutb, bout, (float*)d_out, nullptr, nullptr, E, E);
}

// Round 11
// 367.915 us; speedup vs baseline: 1.9447x; 1.0113x over previous
//
#include <hip/hip_runtime.h>

// MHA forward, MI355X/gfx950 — round 11.
// Change vs R10 (one bucket: pass-1 pipeline depth):
//   Pass-1 K pipeline 1-deep -> 3-deep ROLLED ring over {Kslot, Vslot, Ps}
//   (all free during pass 1; Q-frags hoisted to regs behind a barrier before
//   the ring first touches Ps). Counted waits 8/4/0 (scalar branches, no
//   unroll, no pointer arrays — the R4 failure mode avoided). Prologue
//   pre-stages K0+K1. Reduction section restages K0->Kslot + V0->Vslot for
//   pass 2. Pass 2 byte-identical to R10.
// Kept: XCD swizzle, exp2 builtin, nt stores, 3 blocks/CU, counted vmcnt.

#define DEV __device__ __forceinline__

typedef __attribute__((ext_vector_type(8))) short short8;   // 8 bf16 (MFMA A/B frag)
typedef __attribute__((ext_vector_type(4))) float f32x4;    // MFMA C/D frag

DEV unsigned short f2b(float f) {   // f32 -> bf16 RNE
  union { float f; unsigned u; } v; v.f = f;
  unsigned r = v.u + 0x7fffu + ((v.u >> 16) & 1u);
  return (unsigned short)(r >> 16);
}
DEV unsigned pk2(float lo, float hi) {  // two f32 -> packed bf16x2
  return (unsigned)f2b(lo) | ((unsigned)f2b(hi) << 16);
}
#if __has_builtin(__builtin_amdgcn_exp2f)
DEV float exp2_fast(float x) { return __builtin_amdgcn_exp2f(x); }
#else
DEV float exp2_fast(float x) { return exp2f(x); }
#endif
DEV void gl_lds16(const void* g, void* l) {  // async global->LDS, dest = base + lane*16
  __builtin_amdgcn_global_load_lds(
      (const __attribute__((address_space(1))) void*)g,
      (__attribute__((address_space(3))) void*)l, 16, 0, 0);
}
DEV void bar_lgkm() { asm volatile("s_waitcnt lgkmcnt(0)\n\ts_barrier" ::: "memory"); }

__global__ void cvt_f32_bf16(const float* __restrict__ src, unsigned short* __restrict__ dst, int n) {
  int i = (blockIdx.x * blockDim.x + threadIdx.x) * 4;
  if (i >= n) return;
  float4 v = *(const float4*)(src + i);
  ushort4 o; o.x = f2b(v.x); o.y = f2b(v.y); o.z = f2b(v.z); o.w = f2b(v.w);
  *(ushort4*)(dst + i) = o;
}

// C = A @ B^T + bias; A[M][K], B[N][K] bf16. 128x128 tile, BK=64, 4 waves (2x2).
// MODE 0: fp32 C (ld=N, nontemporal).  MODE 1: QKV special — n<2048 -> bf16 Cqk
// (ld 2048, q cols scaled 0.125*log2e); n>=2048 -> V transposed into Vtg[bh][d][t].
template<int MODE>
__global__ __launch_bounds__(256, 2) void gemm_bt(
    const unsigned short* __restrict__ A,
    const unsigned short* __restrict__ B,
    const float* __restrict__ bias,
    float* __restrict__ Cf,
    unsigned short* __restrict__ Cqk,
    unsigned short* __restrict__ Vtg,
    int N, int K)
{
  constexpr int BK = 64;
  __shared__ __align__(16) unsigned short As[128*BK];
  __shared__ __align__(16) unsigned short Bs[128*BK];
  const int tid = threadIdx.x, lane = tid & 63, wid = tid >> 6;
  const int lhi = lane >> 4, llo = lane & 15;
  const int m0 = blockIdx.y * 128, n0 = blockIdx.x * 128;
  const int wr = wid >> 1, wc = wid & 1;

  f32x4 acc[4][4] = {};

  const int nsteps = K / BK;
  for (int kt = 0; kt < nsteps; ++kt) {
    __syncthreads();
#pragma unroll
    for (int s = 0; s < 4; ++s) {
      int u = wid*4 + s;
      int a = u*1024 + lane*16;
      int t = a >> 7;
      int cb = (a & 127) ^ ((t & 7) << 4);
      int e = kt*BK + (cb >> 1);
      gl_lds16(A + (size_t)(m0 + t)*K + e, (char*)As + u*1024);
      gl_lds16(B + (size_t)(n0 + t)*K + e, (char*)Bs + u*1024);
    }
    __syncthreads();
#pragma unroll
    for (int kk = 0; kk < 2; ++kk) {
      short8 af[4], bfr[4];
#pragma unroll
      for (int mf = 0; mf < 4; ++mf) {
        int row = wr*64 + mf*16 + llo;
        af[mf] = *(const short8*)((const char*)As + row*128 + ((kk*64 + lhi*16) ^ ((row & 7) << 4)));
      }
#pragma unroll
      for (int nf = 0; nf < 4; ++nf) {
        int row = wc*64 + nf*16 + llo;
        bfr[nf] = *(const short8*)((const char*)Bs + row*128 + ((kk*64 + lhi*16) ^ ((row & 7) << 4)));
      }
#pragma unroll
      for (int mf = 0; mf < 4; ++mf)
#pragma unroll
        for (int nf = 0; nf < 4; ++nf)
          acc[mf][nf] = __builtin_amdgcn_mfma_f32_16x16x32_bf16(af[mf], bfr[nf], acc[mf][nf], 0, 0, 0);
    }
  }
  // epilogue (C/D: row = lhi*4+r, col = llo)
  if (MODE == 0) {
#pragma unroll
    for (int mf = 0; mf < 4; ++mf)
#pragma unroll
      for (int nf = 0; nf < 4; ++nf) {
        int n = n0 + wc*64 + nf*16 + llo;
        float bv = bias[n];
#pragma unroll
        for (int r = 0; r < 4; ++r) {
          int m = m0 + wr*64 + mf*16 + lhi*4 + r;
          __builtin_nontemporal_store(acc[mf][nf][r] + bv, &Cf[(size_t)m*N + n]);
        }
      }
  } else {
    if (n0 < 2048) {  // Q/K region
#pragma unroll
      for (int mf = 0; mf < 4; ++mf)
#pragma unroll
        for (int nf = 0; nf < 4; ++nf) {
          int n = n0 + wc*64 + nf*16 + llo;
          float bv = bias[n];
          // q pre-scale folds softmax scale AND log2e (exp -> exp2)
          float sc = (n < 1024) ? 0.125f * 1.44269504088896f : 1.0f;
#pragma unroll
          for (int r = 0; r < 4; ++r) {
            int m = m0 + wr*64 + mf*16 + lhi*4 + r;
            Cqk[(size_t)m*2048 + n] = f2b((acc[mf][nf][r] + bv) * sc);
          }
        }
    } else {          // V region -> transposed Vtg[bh][d][t]
#pragma unroll
      for (int mf = 0; mf < 4; ++mf)
#pragma unroll
        for (int nf = 0; nf < 4; ++nf) {
          int n = n0 + wc*64 + nf*16 + llo;
          float bv = bias[n];
          int hh = (n - 2048) >> 6, d = (n - 2048) & 63;
          int m = m0 + wr*64 + mf*16 + lhi*4;
          int bb = m >> 11, t = m & 2047;
          ushort4 o;
          o.x = f2b(acc[mf][nf][0] + bv);
          o.y = f2b(acc[mf][nf][1] + bv);
          o.z = f2b(acc[mf][nf][2] + bv);
          o.w = f2b(acc[mf][nf][3] + bv);
          *(ushort4*)(Vtg + ((size_t)((bb << 4) + hh)*64 + d)*2048 + t) = o;
        }
    }
  }
}

// Fused attention. Block = (b,h,qt): 64 q-rows, 4 waves, 3 blocks/CU.
// Wave w owns t-cols [w*32,w*32+32) for scores (mfma(K,Q): D[t][q]) and
// q-rows [w*16,w*16+16) for PV (mfma(Vt,P): D[d][q]).
// K rows in LDS are wave-private (wave w stages & reads rows [32w,32w+32)).
__global__ __launch_bounds__(256, 3) void mha_fused(
    const unsigned short* __restrict__ qk,    // [8192][2048] bf16 (q scaled)
    const unsigned short* __restrict__ vtg,   // [64 bh][64 d][2048 t] bf16
    float* __restrict__ probs,                // [64 bh][2048][2048] f32
    unsigned short* __restrict__ attnb)       // [8192][1024] bf16
{
  constexpr int T = 2048, LD = 2048, QB = 64, TB = 128, NT = T / TB;
  __shared__ __align__(16) unsigned short Kslot[TB*64];   // 16 KB (ring0; pass2 K)
  __shared__ __align__(16) unsigned short Vslot[64*TB];   // 16 KB (ring1; pass2 V)
  __shared__ __align__(16) unsigned short Ps[QB*TB];      // 16 KB (ring2; prologue Q; pass2 P)
  __shared__ float lsum[4][QB];
  __shared__ float linv[QB];

  const int tid = threadIdx.x, lane = tid & 63, wid = tid >> 6;
  const int lhi = lane >> 4, llo = lane & 15;
  // XCD swizzle (T1): wgid = (bid%8)*256 + bid/8 (bijective, 2048%8==0).
  const int wg = ((blockIdx.x & 7) << 8) | (blockIdx.x >> 3);
  const int qt = wg & 31, bh = wg >> 5;
  const int bb = bh >> 4, h = bh & 15;
  const int q0 = qt * QB;
  const size_t tokQ = (size_t)bb*T + q0;

  auto stageK = [&](int tt, unsigned short* buf) {
#pragma unroll
    for (int s = 0; s < 4; ++s) {
      int u = wid*4 + s;
      int a = u*1024 + lane*16;
      int tr = a >> 7;
      int cb = (a & 127) ^ ((tr & 7) << 4);
      gl_lds16(qk + ((size_t)bb*T + tt*TB + tr)*LD + 1024 + h*64 + (cb >> 1),
               (char*)buf + u*1024);
    }
  };
  auto stageV = [&](int tt) {
#pragma unroll
    for (int s = 0; s < 4; ++s) {
      int u = wid*4 + s;
      int a = u*1024 + lane*16;
      int d = a >> 8;
      int cb = (a & 255) ^ ((d & 7) << 4);
      gl_lds16(vtg + ((size_t)bh*64 + d)*T + tt*TB + (cb >> 1),
               (char*)Vslot + u*1024);
    }
  };
  auto bsel = [&](int m) -> unsigned short* {
    return (m == 0) ? Kslot : ((m == 1) ? Vslot : Ps);
  };

  // ---- prologue: Q (into Ps region, 2/wave) + K0->Kslot + K1->Vslot ----
#pragma unroll
  for (int s = 0; s < 2; ++s) {
    int u = wid*2 + s;
    int a = u*1024 + lane*16;
    int tr = a >> 7;
    int cb = (a & 127) ^ ((tr & 7) << 4);
    gl_lds16(qk + (tokQ + tr)*LD + h*64 + (cb >> 1), (char*)Ps + u*1024);
  }
  stageK(0, Kslot);
  stageK(1, Vslot);
  asm volatile("s_waitcnt vmcnt(8)" ::: "memory");   // own Q done (K0,K1 in flight)
  __builtin_amdgcn_s_barrier();                      // publish Q

  // Q fragments in registers (loop-invariant)
  short8 qfr[4][2];
#pragma unroll
  for (int qf = 0; qf < 4; ++qf)
#pragma unroll
    for (int kk = 0; kk < 2; ++kk) {
      int row = qf*16 + llo;
      qfr[qf][kk] = *(const short8*)((const char*)Ps + row*128 + ((kk*64 + lhi*16) ^ ((row & 7) << 4)));
    }
  // all waves done reading Q from Ps before the ring stages K2 into Ps
  bar_lgkm();

  // ---------------- pass 1: denominators (3-deep rolled ring, no barriers) ----------------
  float part[4] = {0.f, 0.f, 0.f, 0.f};
  int m3 = 0;   // tt % 3
  int s3 = 2;   // (tt+2) % 3
  for (int tt = 0; tt < NT; ++tt) {
    if (tt + 2 < NT) stageK(tt + 2, bsel(s3));
    if (tt + 2 < NT)      asm volatile("s_waitcnt vmcnt(8)" ::: "memory");  // own K(tt) landed
    else if (tt + 1 < NT) asm volatile("s_waitcnt vmcnt(4)" ::: "memory");
    else                  asm volatile("s_waitcnt vmcnt(0)" ::: "memory");
    const unsigned short* cur = bsel(m3);
    f32x4 sacc[2][4] = {};
#pragma unroll
    for (int kk = 0; kk < 2; ++kk) {
      short8 kf[2];
#pragma unroll
      for (int tf = 0; tf < 2; ++tf) {
        int row = wid*32 + tf*16 + llo;
        kf[tf] = *(const short8*)((const char*)cur + row*128 + ((kk*64 + lhi*16) ^ ((row & 7) << 4)));
      }
#pragma unroll
      for (int tf = 0; tf < 2; ++tf)
#pragma unroll
        for (int qf = 0; qf < 4; ++qf)
          sacc[tf][qf] = __builtin_amdgcn_mfma_f32_16x16x32_bf16(kf[tf], qfr[qf][kk], sacc[tf][qf], 0, 0, 0);
    }
#pragma unroll
    for (int tf = 0; tf < 2; ++tf)
#pragma unroll
      for (int qf = 0; qf < 4; ++qf)
#pragma unroll
        for (int r = 0; r < 4; ++r)
          part[qf] += exp2_fast(sacc[tf][qf][r]);
    m3 = (m3 + 1 == 3) ? 0 : m3 + 1;
    s3 = (s3 + 1 == 3) ? 0 : s3 + 1;
  }

  // reduce: wave-local over lhi groups, then cross-wave via LDS
#pragma unroll
  for (int qf = 0; qf < 4; ++qf) {
    float v = part[qf];
    v += __shfl_xor(v, 16);
    v += __shfl_xor(v, 32);
    if (lhi == 0) lsum[wid][qf*16 + llo] = v;
  }
  bar_lgkm();                                 // lsum visible (all waves past pass 1)
  if (tid < QB) linv[tid] = 1.0f / (lsum[0][tid] + lsum[1][tid] + lsum[2][tid] + lsum[3][tid]);
  stageK(0, Kslot);                           // K0 for pass 2
  stageV(0);                                  // V0 for pass 2
  bar_lgkm();                                 // linv visible
  float lr[4];
#pragma unroll
  for (int qf = 0; qf < 4; ++qf) lr[qf] = linv[qf*16 + llo];

  // ---------------- pass 2: probs + PV (single K buffer, uniform vmcnt(12)) ----------------
  f32x4 pv[4] = {};
  for (int tt = 0; tt < NT; ++tt) {
    // top: own K(tt) landed. Steady state keeps stores(tt-1)8 + V(tt)4 = 12.
    if (tt == 0) asm volatile("s_waitcnt vmcnt(4)"  ::: "memory");
    else         asm volatile("s_waitcnt vmcnt(12)" ::: "memory");
    // A: scores from own Kslot rows
    f32x4 sacc[2][4] = {};
#pragma unroll
    for (int kk = 0; kk < 2; ++kk) {
      short8 kf[2];
#pragma unroll
      for (int tf = 0; tf < 2; ++tf) {
        int row = wid*32 + tf*16 + llo;
        kf[tf] = *(const short8*)((const char*)Kslot + row*128 + ((kk*64 + lhi*16) ^ ((row & 7) << 4)));
      }
#pragma unroll
      for (int tf = 0; tf < 2; ++tf)
#pragma unroll
        for (int qf = 0; qf < 4; ++qf)
          sacc[tf][qf] = __builtin_amdgcn_mfma_f32_16x16x32_bf16(kf[tf], qfr[qf][kk], sacc[tf][qf], 0, 0, 0);
    }
    // own ds_reads complete, then overwrite own K rows with K(tt+1)
    asm volatile("s_waitcnt lgkmcnt(0)" ::: "memory");
    __builtin_amdgcn_sched_barrier(0);
    stageK((tt + 1) & 15, Kslot);                    // dummy wrap at tt=15
    // B: exp2, normalize, pack Ps (b64 ds), nt-store probs directly
#pragma unroll
    for (int tf = 0; tf < 2; ++tf)
#pragma unroll
      for (int qf = 0; qf < 4; ++qf) {
        float p0 = exp2_fast(sacc[tf][qf][0]) * lr[qf];
        float p1 = exp2_fast(sacc[tf][qf][1]) * lr[qf];
        float p2 = exp2_fast(sacc[tf][qf][2]) * lr[qf];
        float p3 = exp2_fast(sacc[tf][qf][3]) * lr[qf];
        int q = qf*16 + llo;
        int t0 = wid*32 + tf*16 + lhi*4;
        uint2 w2; w2.x = pk2(p0, p1); w2.y = pk2(p2, p3);
        *(uint2*)((char*)Ps + q*256 + ((t0*2) ^ ((q & 7) << 4))) = w2;
        f32x4 pv4; pv4[0] = 8.f*p0; pv4[1] = 8.f*p1; pv4[2] = 8.f*p2; pv4[3] = 8.f*p3;
        __builtin_nontemporal_store(pv4,
            (f32x4*)&probs[((size_t)bh*T + q0 + q)*T + tt*TB + t0]);
      }
    // B1: V(tt) landed (keep K(tt+1)4 + stores(tt)8 = 12), publish Ps
    asm volatile("s_waitcnt vmcnt(12) lgkmcnt(0)\n\ts_barrier" ::: "memory");
    // D: PV (reads Ps + Vslot)
#pragma unroll
    for (int kk2 = 0; kk2 < 4; ++kk2) {
      int rq = wid*16 + llo;
      short8 pb = *(const short8*)((const char*)Ps + rq*256 + ((kk2*64 + lhi*16) ^ ((rq & 7) << 4)));
#pragma unroll
      for (int mf = 0; mf < 4; ++mf) {
        int rd = mf*16 + llo;
        short8 va = *(const short8*)((const char*)Vslot + rd*256 + ((kk2*64 + lhi*16) ^ ((rd & 7) << 4)));
        pv[mf] = __builtin_amdgcn_mfma_f32_16x16x32_bf16(va, pb, pv[mf], 0, 0, 0);
      }
    }
    // B2: all waves done with Ps/Vslot before overwrite next iter
    asm volatile("s_waitcnt lgkmcnt(0)\n\ts_barrier" ::: "memory");
    // F: issue next V
    stageV((tt + 1) & 15);                           // dummy wrap at tt=15
  }

  // attn out: D[d][q], lane has 4 consecutive d at q = wid*16+llo
#pragma unroll
  for (int mf = 0; mf < 4; ++mf) {
    int q = wid*16 + llo;
    int d0 = mf*16 + lhi*4;
    ushort4 o;
    o.x = f2b(pv[mf][0]); o.y = f2b(pv[mf][1]);
    o.z = f2b(pv[mf][2]); o.w = f2b(pv[mf][3]);
    *(ushort4*)(attnb + (tokQ + q)*1024 + h*64 + d0) = o;
  }
}

extern "C" void kernel_launch(void* const* d_in, const int* in_sizes, int n_in,
                              void* d_out, int out_size, void* d_ws, size_t ws_size,
                              hipStream_t stream) {
  (void)in_sizes; (void)n_in; (void)out_size; (void)ws_size;
  const float* x    = (const float*)d_in[0];
  const float* wqkv = (const float*)d_in[1];
  const float* bqkv = (const float*)d_in[2];
  const float* wout = (const float*)d_in[3];
  const float* bout = (const float*)d_in[4];

  constexpr int T = 2048, E = 1024;
  constexpr int M = 4 * T;
  constexpr size_t NX   = (size_t)M * E;
  constexpr size_t NW1  = (size_t)3 * E * E;
  constexpr size_t NW2  = (size_t)E * E;
  constexpr size_t NQK  = (size_t)M * 2048;
  constexpr size_t NVT  = (size_t)64 * 64 * T;

  char* ws = (char*)d_ws;
  unsigned short* xb    = (unsigned short*)ws;  ws += NX  * 2;
  unsigned short* wqkvb = (unsigned short*)ws;  ws += NW1 * 2;
  unsigned short* woutb = (unsigned short*)ws;  ws += NW2 * 2;
  unsigned short* qkb   = (unsigned short*)ws;  ws += NQK * 2;
  unsigned short* vtg   = (unsigned short*)ws;  ws += NVT * 2;
  unsigned short* attnb = (unsigned short*)ws;  ws += NX  * 2;

  cvt_f32_bf16<<<(int)(NX  / 1024), 256, 0, stream>>>(x,    xb,    (int)NX);
  cvt_f32_bf16<<<(int)(NW1 / 1024), 256, 0, stream>>>(wqkv, wqkvb, (int)NW1);
  cvt_f32_bf16<<<(int)(NW2 / 1024), 256, 0, stream>>>(wout, woutb, (int)NW2);

  gemm_bt<1><<<dim3(3*E/128, M/128), 256, 0, stream>>>(
      xb, wqkvb, bqkv, nullptr, qkb, vtg, 3*E, E);

  float* probsOut = (float*)d_out + NX;
  mha_fused<<<4*16*(T/64), 256, 0, stream>>>(qkb, vtg, probsOut, attnb);

  gemm_bt<0><<<dim3(E/128, M/128), 256, 0, stream>>>(
      attnb, woutb, bout, (float*)d_out, nullptr, nullptr, E, E);
}